// Round 8
// baseline (375.324 us; speedup 1.0000x reference)
//
#include <hip/hip_runtime.h>
#include <hip/hip_bf16.h>

typedef unsigned short ush;
typedef unsigned int uint32;
typedef __attribute__((ext_vector_type(8))) short s8v;   // 8 bf16 (4 VGPRs)
typedef __attribute__((ext_vector_type(4))) float f4v;   // MFMA accumulator

#define NB 16
#define NT 128
#define NTM 128
#define NV 25
#define NCIN 64
#define NCM 256
#define NH 8
#define ND 32
#define NC 256
#define NK 3
#define NKC 768
#define LN_EPS 1e-6f
#define QSCALE 0.17677669529663687f

__device__ __forceinline__ float bf2f(ush u) {
    union { uint32 i; float f; } x; x.i = ((uint32)u) << 16; return x.f;
}
__device__ __forceinline__ ush f2bf(float f) {
    union { float f; uint32 i; } x; x.f = f;
    uint32 r = x.i + 0x7FFFu + ((x.i >> 16) & 1u);
    return (ush)(r >> 16);
}

// -------- dtype detector (f32 vs bf16 device buffers) --------
__global__ __launch_bounds__(256) void k_detect(const uint32* __restrict__ xw,
                                               int* __restrict__ flag)
{
    __shared__ int cnt;
    if (threadIdx.x == 0) cnt = 0;
    __syncthreads();
    int c = 0;
    for (int i = 0; i < 4; ++i) {
        uint32 u = xw[threadIdx.x + 256 * i];
        uint32 e = (u >> 7) & 0xFF;
        c += (e >= 100 && e <= 135) ? 1 : 0;
    }
    atomicAdd(&cnt, c);
    __syncthreads();
    if (threadIdx.x == 0) *flag = (cnt > 700) ? 1 : 0;   // 1 = bf16, 0 = f32
}

// src (f32 or bf16) -> dst f32 (for A)
__global__ __launch_bounds__(256) void k_convF(const void* __restrict__ src,
                                               float* __restrict__ dst, int n,
                                               const int* __restrict__ flag)
{
    const bool isbf = (*flag != 0);
    int i = blockIdx.x * 256 + threadIdx.x;
    if (i < n) dst[i] = isbf ? bf2f(((const ush*)src)[i]) : ((const float*)src)[i];
}

// -------- single-launch converter: plain copies + [K,N]->[N,K] transposes --------
struct CvEnt { const void* src; ush* dst; int n; int K; int N; int blk0; };
struct CvTab { CvEnt e[16]; };

__global__ __launch_bounds__(256) void k_convall(CvTab tab, const int* __restrict__ flag)
{
    const bool isbf = (*flag != 0);
    const int bi = (int)blockIdx.x;
    int ei = 0;
    #pragma unroll
    for (int i = 1; i < 16; ++i) if (bi >= tab.e[i].blk0) ei = i;
    const CvEnt& e = tab.e[ei];
    const int idx = (bi - e.blk0) * 256 + (int)threadIdx.x;
    if (idx >= e.n) return;
    int s;
    if (e.K == 0) s = idx;
    else { int n = idx / e.K, k = idx - n * e.K; s = k * e.N + n; }
    e.dst[idx] = isbf ? ((const ush*)e.src)[s] : f2bf(((const float*)e.src)[s]);
}

// -------- MFMA GEMM: C[M, cols n0..] = A[M,K] @ Bt[N,K]^T --------
__global__ __launch_bounds__(256) void k_gemm(
    const ush* __restrict__ A, const ush* __restrict__ Bt, ush* __restrict__ C,
    int M, int K, int ldC)
{
    const int n0 = blockIdx.x * 128, m0 = blockIdx.y * 128;
    const int tid = threadIdx.x, w = tid >> 6, l = tid & 63;
    __shared__ ush As[8192], Bs[8192];   // 16KB each: 128 rows x 128B, linear
    const char* AsB = (const char*)As;
    const char* BsB = (const char*)Bs;
    const int rl = l >> 3, cc = l & 7;
    f4v acc[4][4] = {};
    const int wm = w >> 1, wn = w & 1;

    for (int kt = 0; kt < K; kt += 64) {
        __syncthreads();
        #pragma unroll
        for (int j = 0; j < 4; ++j) {
            const int r = (w * 4 + j) * 8 + rl;
            const int sc = (cc ^ (r & 7)) * 8;
            const ush* ga = &A[(size_t)(m0 + r) * K + kt + sc];
            const ush* gb = &Bt[(size_t)(n0 + r) * K + kt + sc];
            __builtin_amdgcn_global_load_lds(
                (const __attribute__((address_space(1))) uint32*)ga,
                (__attribute__((address_space(3))) uint32*)&As[(w * 4 + j) * 512], 16, 0, 0);
            __builtin_amdgcn_global_load_lds(
                (const __attribute__((address_space(1))) uint32*)gb,
                (__attribute__((address_space(3))) uint32*)&Bs[(w * 4 + j) * 512], 16, 0, 0);
        }
        __syncthreads();
        #pragma unroll
        for (int ks = 0; ks < 2; ++ks) {
            const int ko = ks * 64 + (l >> 4) * 16;
            s8v a[4], b[4];
            #pragma unroll
            for (int mi = 0; mi < 4; ++mi) {
                const int ra = wm * 64 + mi * 16 + (l & 15);
                a[mi] = *(const s8v*)(AsB + ra * 128 + (ko ^ ((ra & 7) << 4)));
            }
            #pragma unroll
            for (int ni = 0; ni < 4; ++ni) {
                const int rb = wn * 64 + ni * 16 + (l & 15);
                b[ni] = *(const s8v*)(BsB + rb * 128 + (ko ^ ((rb & 7) << 4)));
            }
            #pragma unroll
            for (int mi = 0; mi < 4; ++mi)
                #pragma unroll
                for (int ni = 0; ni < 4; ++ni)
                    acc[mi][ni] = __builtin_amdgcn_mfma_f32_16x16x32_bf16(a[mi], b[ni],
                                                                          acc[mi][ni], 0, 0, 0);
        }
    }
    const int col = n0 + wn * 64 + (l & 15);
    #pragma unroll
    for (int mi = 0; mi < 4; ++mi) {
        const int row_base = m0 + wm * 64 + mi * 16 + (l >> 4) * 4;
        #pragma unroll
        for (int ni = 0; ni < 4; ++ni)
            #pragma unroll
            for (int r = 0; r < 4; ++r)
                C[(size_t)(row_base + r) * ldC + col + ni * 16] = f2bf(acc[mi][ni][r]);
    }
}

// -------- MFMA attention: 1 wave = 1 (b,h,v) head; zero LDS --------
template<int MASKED>
__global__ __launch_bounds__(64) void k_attn_mfma(
    const ush* __restrict__ QKV, ush* __restrict__ O)
{
    const int v = blockIdx.x, h = blockIdx.y, b = blockIdx.z;
    const int l = threadIdx.x, g = l >> 4, c = l & 15;
    const size_t tokStride = (size_t)NV * NKC;
    const ush* base = QKV + ((size_t)b * NT * NV + v) * NKC;

    s8v kf[8];
    const int koff = 256 + h * ND + g * 8;
    #pragma unroll
    for (int si = 0; si < 8; ++si)
        kf[si] = *(const s8v*)(base + (size_t)(16 * si + c) * tokStride + koff);

    s8v vf[4][2];
    #pragma unroll
    for (int ks = 0; ks < 4; ++ks)
        #pragma unroll
        for (int ni = 0; ni < 2; ++ni) {
            const int voff = 512 + h * ND + 16 * ni + c;
            s8v tmp;
            #pragma unroll
            for (int j = 0; j < 8; ++j)
                tmp[j] = (short)base[(size_t)(32 * ks + 8 * g + j) * tokStride + voff];
            vf[ks][ni] = tmp;
        }

    ush* og = O + ((size_t)b * NT * NV + v) * NC + h * ND;
    const int qoff = h * ND + g * 8;
    const int ga = (g & 1) * 2;
    const int l1 = ga * 16 + c, l2 = l1 + 16;
    const bool hisel = (g >> 1) != 0;

    for (int t16 = 0; t16 < 8; ++t16) {
        s8v qf = *(const s8v*)(base + (size_t)(16 * t16 + c) * tokStride + qoff);
        f4v st[8];
        #pragma unroll
        for (int si = 0; si < 8; ++si)
            st[si] = __builtin_amdgcn_mfma_f32_16x16x32_bf16(kf[si], qf,
                                                             (f4v){0.f, 0.f, 0.f, 0.f}, 0, 0, 0);
        const int t = 16 * t16 + c;
        if (MASKED) {
            #pragma unroll
            for (int si = 0; si < 8; ++si)
                #pragma unroll
                for (int r = 0; r < 4; ++r)
                    if (16 * si + 4 * g + r > t) st[si][r] = -1e30f;
        }
        float mx = -1e30f;
        #pragma unroll
        for (int si = 0; si < 8; ++si)
            #pragma unroll
            for (int r = 0; r < 4; ++r) mx = fmaxf(mx, st[si][r]);
        mx = fmaxf(mx, __shfl_xor(mx, 16));
        mx = fmaxf(mx, __shfl_xor(mx, 32));
        float sm = 0.f;
        #pragma unroll
        for (int si = 0; si < 8; ++si)
            #pragma unroll
            for (int r = 0; r < 4; ++r) {
                float e = __expf((st[si][r] - mx) * QSCALE);
                st[si][r] = e;
                sm += e;
            }
        sm += __shfl_xor(sm, 16);
        sm += __shfl_xor(sm, 32);
        const float inv = 1.f / sm;
        uint32 u[8][2];
        #pragma unroll
        for (int si = 0; si < 8; ++si) {
            float e0 = st[si][0] * inv, e1 = st[si][1] * inv;
            float e2 = st[si][2] * inv, e3 = st[si][3] * inv;
            asm("v_cvt_pk_bf16_f32 %0, %1, %2" : "=v"(u[si][0]) : "v"(e0), "v"(e1));
            asm("v_cvt_pk_bf16_f32 %0, %1, %2" : "=v"(u[si][1]) : "v"(e2), "v"(e3));
        }
        f4v o[2] = {};
        #pragma unroll
        for (int ks = 0; ks < 4; ++ks) {
            uint32 w0a = __shfl(u[2 * ks][0], l1),     w0b = __shfl(u[2 * ks][1], l1);
            uint32 w0c = __shfl(u[2 * ks][0], l2),     w0d = __shfl(u[2 * ks][1], l2);
            uint32 w1a = __shfl(u[2 * ks + 1][0], l1), w1b = __shfl(u[2 * ks + 1][1], l1);
            uint32 w1c = __shfl(u[2 * ks + 1][0], l2), w1d = __shfl(u[2 * ks + 1][1], l2);
            union { uint32 w[4]; s8v s; } pa;
            pa.w[0] = hisel ? w1a : w0a;
            pa.w[1] = hisel ? w1b : w0b;
            pa.w[2] = hisel ? w1c : w0c;
            pa.w[3] = hisel ? w1d : w0d;
            o[0] = __builtin_amdgcn_mfma_f32_16x16x32_bf16(pa.s, vf[ks][0], o[0], 0, 0, 0);
            o[1] = __builtin_amdgcn_mfma_f32_16x16x32_bf16(pa.s, vf[ks][1], o[1], 0, 0, 0);
        }
        #pragma unroll
        for (int ni = 0; ni < 2; ++ni)
            #pragma unroll
            for (int r = 0; r < 4; ++r)
                og[(size_t)(16 * t16 + 4 * g + r) * (NV * NC) + 16 * ni + c] = f2bf(o[ni][r]);
    }
}

// ---------------- row LayerNorm (unbiased std), in place, 1 wave = 1 row ----------------
__global__ __launch_bounds__(256) void k_ln(
    ush* __restrict__ buf, const ush* __restrict__ g, const ush* __restrict__ bb)
{
    const int row = blockIdx.x * 4 + (threadIdx.x >> 6);
    const int lane = threadIdx.x & 63;
    ush* p = buf + (size_t)row * NC + lane * 4;
    uint2 u = *(uint2*)p;
    float x0 = bf2f((ush)(u.x & 0xffff)), x1 = bf2f((ush)(u.x >> 16));
    float x2 = bf2f((ush)(u.y & 0xffff)), x3 = bf2f((ush)(u.y >> 16));
    float s = x0 + x1 + x2 + x3;
    float q = x0 * x0 + x1 * x1 + x2 * x2 + x3 * x3;
    #pragma unroll
    for (int o = 32; o; o >>= 1) { s += __shfl_xor(s, o); q += __shfl_xor(q, o); }
    float mean = s * (1.f / 256.f);
    float var = fmaxf((q - 256.f * mean * mean) * (1.f / 255.f), 0.f);
    float inv = 1.f / (sqrtf(var) + LN_EPS);
    float o0 = bf2f(g[lane * 4 + 0]) * (x0 - mean) * inv + bf2f(bb[lane * 4 + 0]);
    float o1 = bf2f(g[lane * 4 + 1]) * (x1 - mean) * inv + bf2f(bb[lane * 4 + 1]);
    float o2 = bf2f(g[lane * 4 + 2]) * (x2 - mean) * inv + bf2f(bb[lane * 4 + 2]);
    float o3 = bf2f(g[lane * 4 + 3]) * (x3 - mean) * inv + bf2f(bb[lane * 4 + 3]);
    uint32 lo = (uint32)f2bf(o0) | ((uint32)f2bf(o1) << 16);
    uint32 hi = (uint32)f2bf(o2) | ((uint32)f2bf(o3) << 16);
    *(uint2*)p = make_uint2(lo, hi);
}

// -------- GCN contraction + bias + LayerNorm; coalesced direct loads, --------
// -------- 5-way independent accumulators (breaks the 75-FMA dep chain) --------
__global__ __launch_bounds__(256) void k_gcn(
    const ush* __restrict__ xw, const float* __restrict__ Af,
    const ush* __restrict__ bg, const ush* __restrict__ g3, const ush* __restrict__ b3,
    float* __restrict__ outp)
{
    const int t = blockIdx.x, b = blockIdx.y;
    const int tid = threadIdx.x;
    __shared__ float h3s[NV * NC];   // 25.6KB
    __shared__ float cs[80];

    const ush* xr = xw + ((size_t)(b * NT + t)) * NV * NKC;
    // 75 fully-coalesced loads (consecutive tid -> consecutive addresses)
    float xv[75];
    #pragma unroll
    for (int v = 0; v < NV; ++v)
        #pragma unroll
        for (int k = 0; k < NK; ++k)
            xv[v * 3 + k] = bf2f(xr[v * NKC + k * NC + tid]);
    if (tid < 75) {
        int k = tid / 25, w = tid - k * 25;
        float s = 0.f;
        #pragma unroll
        for (int v = 0; v < NV; ++v) s += Af[k * 625 + v * 25 + w];
        cs[tid] = s;
    }
    float bgv[3];
    #pragma unroll
    for (int k = 0; k < NK; ++k) bgv[k] = bf2f(bg[k * NC + tid]);
    __syncthreads();
    #pragma unroll
    for (int w5 = 0; w5 < 5; ++w5) {
        float a[5];
        #pragma unroll
        for (int j = 0; j < 5; ++j) {
            const int w = w5 * 5 + j;
            a[j] = bgv[0] * cs[w] + bgv[1] * cs[25 + w] + bgv[2] * cs[50 + w];
        }
        #pragma unroll
        for (int k = 0; k < NK; ++k)
            #pragma unroll
            for (int v = 0; v < NV; ++v) {
                const float x = xv[v * 3 + k];
                #pragma unroll
                for (int j = 0; j < 5; ++j)
                    a[j] += Af[k * 625 + v * 25 + w5 * 5 + j] * x;   // uniform -> s_load
            }
        #pragma unroll
        for (int j = 0; j < 5; ++j) h3s[(w5 * 5 + j) * NC + tid] = a[j];
    }
    __syncthreads();
    {
        const int wv = tid >> 6, lane = tid & 63;
        for (int w = wv; w < NV; w += 4) {
            float4 xq = *(const float4*)&h3s[w * NC + lane * 4];
            float s = xq.x + xq.y + xq.z + xq.w;
            float q = xq.x * xq.x + xq.y * xq.y + xq.z * xq.z + xq.w * xq.w;
            #pragma unroll
            for (int o = 32; o; o >>= 1) { s += __shfl_xor(s, o); q += __shfl_xor(q, o); }
            float mean = s * (1.f / 256.f);
            float var = fmaxf((q - 256.f * mean * mean) * (1.f / 255.f), 0.f);
            float inv = 1.f / (sqrtf(var) + LN_EPS);
            float o0 = bf2f(g3[lane * 4 + 0]) * (xq.x - mean) * inv + bf2f(b3[lane * 4 + 0]);
            float o1 = bf2f(g3[lane * 4 + 1]) * (xq.y - mean) * inv + bf2f(b3[lane * 4 + 1]);
            float o2 = bf2f(g3[lane * 4 + 2]) * (xq.z - mean) * inv + bf2f(b3[lane * 4 + 2]);
            float o3 = bf2f(g3[lane * 4 + 3]) * (xq.w - mean) * inv + bf2f(b3[lane * 4 + 3]);
            float* op = outp + (((size_t)(b * NT + t)) * NV + w) * NC + lane * 4;
            *(float4*)op = make_float4(o0, o1, o2, o3);
        }
    }
}

extern "C" void kernel_launch(void* const* d_in, const int* in_sizes, int n_in,
                              void* d_out, int out_size, void* d_ws, size_t ws_size,
                              hipStream_t stream)
{
    const size_t NTOK = (size_t)NB * NT * NV;   // 51200
    char* ws = (char*)d_ws;
    int* flag = (int*)ws;
    float* Af = (float*)(ws + 256);             // A as f32, 7.5KB
    ush* bufA = (ush*)(ws + 8192);              // [M,768]  78.6MB
    ush* bufB = bufA + NTOK * NKC;              // [M,256]  26.2MB
    ush* conv = bufB + NTOK * NC;

    k_detect<<<1, 256, 0, stream>>>((const uint32*)d_in[0], flag);
    k_convF<<<8, 256, 0, stream>>>(d_in[2], Af, NK * NV * NV, flag);

    // ---- one-launch conversion table ----
    CvTab tab;
    int nent = 0, blk = 0;
    ush* p = conv;
    const ush* cp[18] = {};
    auto add = [&](int idx, int n, int K, int N, ush*& dst_out) {
        tab.e[nent] = { d_in[idx], p, n, K, N, blk };
        dst_out = p;
        blk += (n + 255) / 256;
        p += (size_t)((n + 7) & ~7);
        ++nent;
    };
    ush* d;
    add(0, NB * NT * NV * NCIN, 0, 0, d);  cp[0] = d;
    add(1, NB * NTM * NV * NCM, 0, 0, d);  cp[1] = d;
    add(15, NKC, 0, 0, d);                 cp[15] = d;
    add(7, NC, 0, 0, d);  cp[7] = d;
    add(8, NC, 0, 0, d);  cp[8] = d;
    add(12, NC, 0, 0, d); cp[12] = d;
    add(13, NC, 0, 0, d); cp[13] = d;
    add(16, NC, 0, 0, d); cp[16] = d;
    add(17, NC, 0, 0, d); cp[17] = d;
    ush* w1t;
    add(4, NCIN * NC, NCIN, NC, w1t);      // [256][64] q
    add(5, NCIN * NC, NCIN, NC, d);        // k  (contiguous after q)
    add(6, NCIN * NC, NCIN, NC, d);        // v
    ush* wq2t;
    add(9, NC * NC, NC, NC, wq2t);         // [256][256]
    ush* wkv2t;
    add(10, NCM * NC, NCM, NC, wkv2t);     // [256][256] k
    add(11, NCM * NC, NCM, NC, d);         // v (contiguous)
    ush* wgt;
    add(14, NC * NKC, NC, NKC, wgt);       // [768][256]
    k_convall<<<blk, 256, 0, stream>>>(tab, flag);

    const int M = (int)NTOK;
    // stage 1: qkv1 = x @ [Wq1|Wk1|Wv1]  -> bufA [M,768]
    k_gemm<<<dim3(6, M / 128), 256, 0, stream>>>(cp[0], w1t, bufA, M, NCIN, NKC);
    k_attn_mfma<1><<<dim3(NV, NH, NB), 64, 0, stream>>>(bufA, bufB);
    k_ln<<<M / 4, 256, 0, stream>>>(bufB, cp[7], cp[8]);
    // stage 2: q2 = h1 @ Wq2 (cols 0-255); kv2 = m @ [Wk2|Wv2] (cols 256-767)
    k_gemm<<<dim3(2, M / 128), 256, 0, stream>>>(bufB, wq2t, bufA, M, NC, NKC);
    k_gemm<<<dim3(4, M / 128), 256, 0, stream>>>(cp[1], wkv2t, bufA + 256, M, NCM, NKC);
    k_attn_mfma<0><<<dim3(NV, NH, NB), 64, 0, stream>>>(bufA, bufB);
    k_ln<<<M / 4, 256, 0, stream>>>(bufB, cp[12], cp[13]);
    // stage 3: xw = h2 @ Wg -> bufA [M,768]; then GCN+LN -> out
    k_gemm<<<dim3(6, M / 128), 256, 0, stream>>>(bufB, wgt, bufA, M, NC, NKC);
    k_gcn<<<dim3(NT, NB), 256, 0, stream>>>(bufA, Af, cp[15], cp[16], cp[17], (float*)d_out);
}

// Round 9
// 341.457 us; speedup vs baseline: 1.0992x; 1.0992x over previous
//
#include <hip/hip_runtime.h>
#include <hip/hip_bf16.h>

typedef unsigned short ush;
typedef unsigned int uint32;
typedef __attribute__((ext_vector_type(8))) short s8v;   // 8 bf16 (4 VGPRs)
typedef __attribute__((ext_vector_type(4))) float f4v;   // MFMA accumulator

#define NB 16
#define NT 128
#define NTM 128
#define NV 25
#define NCIN 64
#define NCM 256
#define NH 8
#define ND 32
#define NC 256
#define NK 3
#define NKC 768
#define LN_EPS 1e-6f
#define QSCALE 0.17677669529663687f

__device__ __forceinline__ float bf2f(ush u) {
    union { uint32 i; float f; } x; x.i = ((uint32)u) << 16; return x.f;
}
__device__ __forceinline__ ush f2bf(float f) {
    union { float f; uint32 i; } x; x.f = f;
    uint32 r = x.i + 0x7FFFu + ((x.i >> 16) & 1u);
    return (ush)(r >> 16);
}

// -------- dtype detector (f32 vs bf16 device buffers) --------
__global__ __launch_bounds__(256) void k_detect(const uint32* __restrict__ xw,
                                               int* __restrict__ flag)
{
    __shared__ int cnt;
    if (threadIdx.x == 0) cnt = 0;
    __syncthreads();
    int c = 0;
    for (int i = 0; i < 4; ++i) {
        uint32 u = xw[threadIdx.x + 256 * i];
        uint32 e = (u >> 7) & 0xFF;
        c += (e >= 100 && e <= 135) ? 1 : 0;
    }
    atomicAdd(&cnt, c);
    __syncthreads();
    if (threadIdx.x == 0) *flag = (cnt > 700) ? 1 : 0;   // 1 = bf16, 0 = f32
}

// A [k][v][w] (f32 or bf16) -> At f32 [w][80] with At[w*80 + k*25 + v]
__global__ __launch_bounds__(256) void k_convA(const void* __restrict__ src,
                                               float* __restrict__ At,
                                               const int* __restrict__ flag)
{
    const bool isbf = (*flag != 0);
    int i = blockIdx.x * 256 + threadIdx.x;
    if (i >= NK * NV * NV) return;
    int k = i / 625, r = i - k * 625, v = r / 25, w = r - v * 25;
    float x = isbf ? bf2f(((const ush*)src)[i]) : ((const float*)src)[i];
    At[w * 80 + k * 25 + v] = x;
}

// -------- single-launch converter: plain copies + [K,N]->[N,K] transposes --------
struct CvEnt { const void* src; ush* dst; int n; int K; int N; int blk0; };
struct CvTab { CvEnt e[16]; };

__global__ __launch_bounds__(256) void k_convall(CvTab tab, const int* __restrict__ flag)
{
    const bool isbf = (*flag != 0);
    const int bi = (int)blockIdx.x;
    int ei = 0;
    #pragma unroll
    for (int i = 1; i < 16; ++i) if (bi >= tab.e[i].blk0) ei = i;
    const CvEnt& e = tab.e[ei];
    const int idx = (bi - e.blk0) * 256 + (int)threadIdx.x;
    if (idx >= e.n) return;
    int s;
    if (e.K == 0) s = idx;
    else { int n = idx / e.K, k = idx - n * e.K; s = k * e.N + n; }
    e.dst[idx] = isbf ? ((const ush*)e.src)[s] : f2bf(((const float*)e.src)[s]);
}

// -------- MFMA GEMM: C[M, cols n0..] = A[M,K] @ Bt[N,K]^T --------
__global__ __launch_bounds__(256) void k_gemm(
    const ush* __restrict__ A, const ush* __restrict__ Bt, ush* __restrict__ C,
    int M, int K, int ldC)
{
    const int n0 = blockIdx.x * 128, m0 = blockIdx.y * 128;
    const int tid = threadIdx.x, w = tid >> 6, l = tid & 63;
    __shared__ ush As[8192], Bs[8192];   // 16KB each: 128 rows x 128B, linear
    const char* AsB = (const char*)As;
    const char* BsB = (const char*)Bs;
    const int rl = l >> 3, cc = l & 7;
    f4v acc[4][4] = {};
    const int wm = w >> 1, wn = w & 1;

    for (int kt = 0; kt < K; kt += 64) {
        __syncthreads();
        #pragma unroll
        for (int j = 0; j < 4; ++j) {
            const int r = (w * 4 + j) * 8 + rl;
            const int sc = (cc ^ (r & 7)) * 8;
            const ush* ga = &A[(size_t)(m0 + r) * K + kt + sc];
            const ush* gb = &Bt[(size_t)(n0 + r) * K + kt + sc];
            __builtin_amdgcn_global_load_lds(
                (const __attribute__((address_space(1))) uint32*)ga,
                (__attribute__((address_space(3))) uint32*)&As[(w * 4 + j) * 512], 16, 0, 0);
            __builtin_amdgcn_global_load_lds(
                (const __attribute__((address_space(1))) uint32*)gb,
                (__attribute__((address_space(3))) uint32*)&Bs[(w * 4 + j) * 512], 16, 0, 0);
        }
        __syncthreads();
        #pragma unroll
        for (int ks = 0; ks < 2; ++ks) {
            const int ko = ks * 64 + (l >> 4) * 16;
            s8v a[4], b[4];
            #pragma unroll
            for (int mi = 0; mi < 4; ++mi) {
                const int ra = wm * 64 + mi * 16 + (l & 15);
                a[mi] = *(const s8v*)(AsB + ra * 128 + (ko ^ ((ra & 7) << 4)));
            }
            #pragma unroll
            for (int ni = 0; ni < 4; ++ni) {
                const int rb = wn * 64 + ni * 16 + (l & 15);
                b[ni] = *(const s8v*)(BsB + rb * 128 + (ko ^ ((rb & 7) << 4)));
            }
            #pragma unroll
            for (int mi = 0; mi < 4; ++mi)
                #pragma unroll
                for (int ni = 0; ni < 4; ++ni)
                    acc[mi][ni] = __builtin_amdgcn_mfma_f32_16x16x32_bf16(a[mi], b[ni],
                                                                          acc[mi][ni], 0, 0, 0);
        }
    }
    const int col = n0 + wn * 64 + (l & 15);
    #pragma unroll
    for (int mi = 0; mi < 4; ++mi) {
        const int row_base = m0 + wm * 64 + mi * 16 + (l >> 4) * 4;
        #pragma unroll
        for (int ni = 0; ni < 4; ++ni)
            #pragma unroll
            for (int r = 0; r < 4; ++r)
                C[(size_t)(row_base + r) * ldC + col + ni * 16] = f2bf(acc[mi][ni][r]);
    }
}

// -------- MFMA attention: 1 wave = 1 (b,h,v) head; zero LDS --------
template<int MASKED>
__global__ __launch_bounds__(64) void k_attn_mfma(
    const ush* __restrict__ QKV, ush* __restrict__ O)
{
    const int v = blockIdx.x, h = blockIdx.y, b = blockIdx.z;
    const int l = threadIdx.x, g = l >> 4, c = l & 15;
    const size_t tokStride = (size_t)NV * NKC;
    const ush* base = QKV + ((size_t)b * NT * NV + v) * NKC;

    s8v kf[8];
    const int koff = 256 + h * ND + g * 8;
    #pragma unroll
    for (int si = 0; si < 8; ++si)
        kf[si] = *(const s8v*)(base + (size_t)(16 * si + c) * tokStride + koff);

    s8v vf[4][2];
    #pragma unroll
    for (int ks = 0; ks < 4; ++ks)
        #pragma unroll
        for (int ni = 0; ni < 2; ++ni) {
            const int voff = 512 + h * ND + 16 * ni + c;
            s8v tmp;
            #pragma unroll
            for (int j = 0; j < 8; ++j)
                tmp[j] = (short)base[(size_t)(32 * ks + 8 * g + j) * tokStride + voff];
            vf[ks][ni] = tmp;
        }

    ush* og = O + ((size_t)b * NT * NV + v) * NC + h * ND;
    const int qoff = h * ND + g * 8;
    const int ga = (g & 1) * 2;
    const int l1 = ga * 16 + c, l2 = l1 + 16;
    const bool hisel = (g >> 1) != 0;

    for (int t16 = 0; t16 < 8; ++t16) {
        s8v qf = *(const s8v*)(base + (size_t)(16 * t16 + c) * tokStride + qoff);
        f4v st[8];
        #pragma unroll
        for (int si = 0; si < 8; ++si)
            st[si] = __builtin_amdgcn_mfma_f32_16x16x32_bf16(kf[si], qf,
                                                             (f4v){0.f, 0.f, 0.f, 0.f}, 0, 0, 0);
        const int t = 16 * t16 + c;
        if (MASKED) {
            #pragma unroll
            for (int si = 0; si < 8; ++si)
                #pragma unroll
                for (int r = 0; r < 4; ++r)
                    if (16 * si + 4 * g + r > t) st[si][r] = -1e30f;
        }
        float mx = -1e30f;
        #pragma unroll
        for (int si = 0; si < 8; ++si)
            #pragma unroll
            for (int r = 0; r < 4; ++r) mx = fmaxf(mx, st[si][r]);
        mx = fmaxf(mx, __shfl_xor(mx, 16));
        mx = fmaxf(mx, __shfl_xor(mx, 32));
        float sm = 0.f;
        #pragma unroll
        for (int si = 0; si < 8; ++si)
            #pragma unroll
            for (int r = 0; r < 4; ++r) {
                float e = __expf((st[si][r] - mx) * QSCALE);
                st[si][r] = e;
                sm += e;
            }
        sm += __shfl_xor(sm, 16);
        sm += __shfl_xor(sm, 32);
        const float inv = 1.f / sm;
        uint32 u[8][2];
        #pragma unroll
        for (int si = 0; si < 8; ++si) {
            float e0 = st[si][0] * inv, e1 = st[si][1] * inv;
            float e2 = st[si][2] * inv, e3 = st[si][3] * inv;
            asm("v_cvt_pk_bf16_f32 %0, %1, %2" : "=v"(u[si][0]) : "v"(e0), "v"(e1));
            asm("v_cvt_pk_bf16_f32 %0, %1, %2" : "=v"(u[si][1]) : "v"(e2), "v"(e3));
        }
        f4v o[2] = {};
        #pragma unroll
        for (int ks = 0; ks < 4; ++ks) {
            uint32 w0a = __shfl(u[2 * ks][0], l1),     w0b = __shfl(u[2 * ks][1], l1);
            uint32 w0c = __shfl(u[2 * ks][0], l2),     w0d = __shfl(u[2 * ks][1], l2);
            uint32 w1a = __shfl(u[2 * ks + 1][0], l1), w1b = __shfl(u[2 * ks + 1][1], l1);
            uint32 w1c = __shfl(u[2 * ks + 1][0], l2), w1d = __shfl(u[2 * ks + 1][1], l2);
            union { uint32 w[4]; s8v s; } pa;
            pa.w[0] = hisel ? w1a : w0a;
            pa.w[1] = hisel ? w1b : w0b;
            pa.w[2] = hisel ? w1c : w0c;
            pa.w[3] = hisel ? w1d : w0d;
            o[0] = __builtin_amdgcn_mfma_f32_16x16x32_bf16(pa.s, vf[ks][0], o[0], 0, 0, 0);
            o[1] = __builtin_amdgcn_mfma_f32_16x16x32_bf16(pa.s, vf[ks][1], o[1], 0, 0, 0);
        }
        #pragma unroll
        for (int ni = 0; ni < 2; ++ni)
            #pragma unroll
            for (int r = 0; r < 4; ++r)
                og[(size_t)(16 * t16 + 4 * g + r) * (NV * NC) + 16 * ni + c] = f2bf(o[ni][r]);
    }
}

// ---------------- row LayerNorm (unbiased std), in place, 1 wave = 1 row ----------------
__global__ __launch_bounds__(256) void k_ln(
    ush* __restrict__ buf, const ush* __restrict__ g, const ush* __restrict__ bb)
{
    const int row = blockIdx.x * 4 + (threadIdx.x >> 6);
    const int lane = threadIdx.x & 63;
    ush* p = buf + (size_t)row * NC + lane * 4;
    uint2 u = *(uint2*)p;
    float x0 = bf2f((ush)(u.x & 0xffff)), x1 = bf2f((ush)(u.x >> 16));
    float x2 = bf2f((ush)(u.y & 0xffff)), x3 = bf2f((ush)(u.y >> 16));
    float s = x0 + x1 + x2 + x3;
    float q = x0 * x0 + x1 * x1 + x2 * x2 + x3 * x3;
    #pragma unroll
    for (int o = 32; o; o >>= 1) { s += __shfl_xor(s, o); q += __shfl_xor(q, o); }
    float mean = s * (1.f / 256.f);
    float var = fmaxf((q - 256.f * mean * mean) * (1.f / 255.f), 0.f);
    float inv = 1.f / (sqrtf(var) + LN_EPS);
    float o0 = bf2f(g[lane * 4 + 0]) * (x0 - mean) * inv + bf2f(bb[lane * 4 + 0]);
    float o1 = bf2f(g[lane * 4 + 1]) * (x1 - mean) * inv + bf2f(bb[lane * 4 + 1]);
    float o2 = bf2f(g[lane * 4 + 2]) * (x2 - mean) * inv + bf2f(bb[lane * 4 + 2]);
    float o3 = bf2f(g[lane * 4 + 3]) * (x3 - mean) * inv + bf2f(bb[lane * 4 + 3]);
    uint32 lo = (uint32)f2bf(o0) | ((uint32)f2bf(o1) << 16);
    uint32 hi = (uint32)f2bf(o2) | ((uint32)f2bf(o3) << 16);
    *(uint2*)p = make_uint2(lo, hi);
}

// -------- GCN contraction + bias + LayerNorm --------
// At[w][80] f32: per-w coefficients CONTIGUOUS -> s_load_dwordx16 batches.
// Runtime w loop (no unroll blow-up); 3 accumulators (per k) break the chain.
__global__ __launch_bounds__(256) void k_gcn(
    const ush* __restrict__ xw, const float* __restrict__ At,
    const ush* __restrict__ bg, const ush* __restrict__ g3, const ush* __restrict__ b3,
    float* __restrict__ outp)
{
    const int t = blockIdx.x, b = blockIdx.y;
    const int tid = threadIdx.x;
    __shared__ float h3s[NV * NC];   // 25.6KB
    __shared__ float cs[80];

    const ush* xr = xw + ((size_t)(b * NT + t)) * NV * NKC;
    // 75 fully-coalesced loads (consecutive tid -> consecutive addresses)
    float xv[75];
    #pragma unroll
    for (int v = 0; v < NV; ++v)
        #pragma unroll
        for (int k = 0; k < NK; ++k)
            xv[v * 3 + k] = bf2f(xr[v * NKC + k * NC + tid]);
    if (tid < 75) {
        int k = tid / 25, w = tid - k * 25;
        float s = 0.f;
        #pragma unroll
        for (int v = 0; v < NV; ++v) s += At[w * 80 + k * 25 + v];
        cs[tid] = s;
    }
    float bgv[3];
    #pragma unroll
    for (int k = 0; k < NK; ++k) bgv[k] = bf2f(bg[k * NC + tid]);
    __syncthreads();
    #pragma unroll 1
    for (int w = 0; w < NV; ++w) {
        const float* aw = At + w * 80;         // uniform base -> s_load_dwordx16
        float a0 = bgv[0] * cs[w];
        float a1 = bgv[1] * cs[25 + w];
        float a2 = bgv[2] * cs[50 + w];
        #pragma unroll
        for (int v = 0; v < NV; ++v) {
            a0 += aw[v]      * xv[v * 3 + 0];
            a1 += aw[25 + v] * xv[v * 3 + 1];
            a2 += aw[50 + v] * xv[v * 3 + 2];
        }
        h3s[w * NC + tid] = a0 + a1 + a2;
    }
    __syncthreads();
    {
        const int wv = tid >> 6, lane = tid & 63;
        for (int w = wv; w < NV; w += 4) {
            float4 xq = *(const float4*)&h3s[w * NC + lane * 4];
            float s = xq.x + xq.y + xq.z + xq.w;
            float q = xq.x * xq.x + xq.y * xq.y + xq.z * xq.z + xq.w * xq.w;
            #pragma unroll
            for (int o = 32; o; o >>= 1) { s += __shfl_xor(s, o); q += __shfl_xor(q, o); }
            float mean = s * (1.f / 256.f);
            float var = fmaxf((q - 256.f * mean * mean) * (1.f / 255.f), 0.f);
            float inv = 1.f / (sqrtf(var) + LN_EPS);
            float o0 = bf2f(g3[lane * 4 + 0]) * (xq.x - mean) * inv + bf2f(b3[lane * 4 + 0]);
            float o1 = bf2f(g3[lane * 4 + 1]) * (xq.y - mean) * inv + bf2f(b3[lane * 4 + 1]);
            float o2 = bf2f(g3[lane * 4 + 2]) * (xq.z - mean) * inv + bf2f(b3[lane * 4 + 2]);
            float o3 = bf2f(g3[lane * 4 + 3]) * (xq.w - mean) * inv + bf2f(b3[lane * 4 + 3]);
            float* op = outp + (((size_t)(b * NT + t)) * NV + w) * NC + lane * 4;
            *(float4*)op = make_float4(o0, o1, o2, o3);
        }
    }
}

extern "C" void kernel_launch(void* const* d_in, const int* in_sizes, int n_in,
                              void* d_out, int out_size, void* d_ws, size_t ws_size,
                              hipStream_t stream)
{
    const size_t NTOK = (size_t)NB * NT * NV;   // 51200
    char* ws = (char*)d_ws;
    int* flag = (int*)ws;
    float* At = (float*)(ws + 256);             // A transposed [25][80] f32, 8KB
    ush* bufA = (ush*)(ws + 16384);             // [M,768]  78.6MB
    ush* bufB = bufA + NTOK * NKC;              // [M,256]  26.2MB
    ush* conv = bufB + NTOK * NC;

    k_detect<<<1, 256, 0, stream>>>((const uint32*)d_in[0], flag);
    k_convA<<<8, 256, 0, stream>>>(d_in[2], At, flag);

    // ---- one-launch conversion table ----
    CvTab tab;
    int nent = 0, blk = 0;
    ush* p = conv;
    const ush* cp[18] = {};
    auto add = [&](int idx, int n, int K, int N, ush*& dst_out) {
        tab.e[nent] = { d_in[idx], p, n, K, N, blk };
        dst_out = p;
        blk += (n + 255) / 256;
        p += (size_t)((n + 7) & ~7);
        ++nent;
    };
    ush* d;
    add(0, NB * NT * NV * NCIN, 0, 0, d);  cp[0] = d;
    add(1, NB * NTM * NV * NCM, 0, 0, d);  cp[1] = d;
    add(15, NKC, 0, 0, d);                 cp[15] = d;
    add(7, NC, 0, 0, d);  cp[7] = d;
    add(8, NC, 0, 0, d);  cp[8] = d;
    add(12, NC, 0, 0, d); cp[12] = d;
    add(13, NC, 0, 0, d); cp[13] = d;
    add(16, NC, 0, 0, d); cp[16] = d;
    add(17, NC, 0, 0, d); cp[17] = d;
    ush* w1t;
    add(4, NCIN * NC, NCIN, NC, w1t);      // [256][64] q
    add(5, NCIN * NC, NCIN, NC, d);        // k  (contiguous after q)
    add(6, NCIN * NC, NCIN, NC, d);        // v
    ush* wq2t;
    add(9, NC * NC, NC, NC, wq2t);         // [256][256]
    ush* wkv2t;
    add(10, NCM * NC, NCM, NC, wkv2t);     // [256][256] k
    add(11, NCM * NC, NCM, NC, d);         // v (contiguous)
    ush* wgt;
    add(14, NC * NKC, NC, NKC, wgt);       // [768][256]
    k_convall<<<blk, 256, 0, stream>>>(tab, flag);

    const int M = (int)NTOK;
    // stage 1: qkv1 = x @ [Wq1|Wk1|Wv1]  -> bufA [M,768]
    k_gemm<<<dim3(6, M / 128), 256, 0, stream>>>(cp[0], w1t, bufA, M, NCIN, NKC);
    k_attn_mfma<1><<<dim3(NV, NH, NB), 64, 0, stream>>>(bufA, bufB);
    k_ln<<<M / 4, 256, 0, stream>>>(bufB, cp[7], cp[8]);
    // stage 2: q2 = h1 @ Wq2 (cols 0-255); kv2 = m @ [Wk2|Wv2] (cols 256-767)
    k_gemm<<<dim3(2, M / 128), 256, 0, stream>>>(bufB, wq2t, bufA, M, NC, NKC);
    k_gemm<<<dim3(4, M / 128), 256, 0, stream>>>(cp[1], wkv2t, bufA + 256, M, NCM, NKC);
    k_attn_mfma<0><<<dim3(NV, NH, NB), 64, 0, stream>>>(bufA, bufB);
    k_ln<<<M / 4, 256, 0, stream>>>(bufB, cp[12], cp[13]);
    // stage 3: xw = h2 @ Wg -> bufA [M,768]; then GCN+LN -> out
    k_gemm<<<dim3(6, M / 128), 256, 0, stream>>>(bufB, wgt, bufA, M, NC, NKC);
    k_gcn<<<dim3(NT, NB), 256, 0, stream>>>(bufA, At, cp[15], cp[16], cp[17], (float*)d_out);
}

// Round 10
// 332.207 us; speedup vs baseline: 1.1298x; 1.0278x over previous
//
#include <hip/hip_runtime.h>
#include <hip/hip_bf16.h>

typedef unsigned short ush;
typedef unsigned int uint32;
typedef __attribute__((ext_vector_type(8))) short s8v;   // 8 bf16 (4 VGPRs)
typedef __attribute__((ext_vector_type(4))) float f4v;   // MFMA accumulator

#define NB 16
#define NT 128
#define NTM 128
#define NV 25
#define NCIN 64
#define NCM 256
#define NH 8
#define ND 32
#define NC 256
#define NK 3
#define NKC 768
#define LN_EPS 1e-6f
#define QSCALE 0.17677669529663687f

__device__ __forceinline__ float bf2f(ush u) {
    union { uint32 i; float f; } x; x.i = ((uint32)u) << 16; return x.f;
}
__device__ __forceinline__ ush f2bf(float f) {
    union { float f; uint32 i; } x; x.f = f;
    uint32 r = x.i + 0x7FFFu + ((x.i >> 16) & 1u);
    return (ush)(r >> 16);
}

// -------- dtype detector (f32 vs bf16 device buffers) --------
__global__ __launch_bounds__(256) void k_detect(const uint32* __restrict__ xw,
                                               int* __restrict__ flag)
{
    __shared__ int cnt;
    if (threadIdx.x == 0) cnt = 0;
    __syncthreads();
    int c = 0;
    for (int i = 0; i < 4; ++i) {
        uint32 u = xw[threadIdx.x + 256 * i];
        uint32 e = (u >> 7) & 0xFF;
        c += (e >= 100 && e <= 135) ? 1 : 0;
    }
    atomicAdd(&cnt, c);
    __syncthreads();
    if (threadIdx.x == 0) *flag = (cnt > 700) ? 1 : 0;   // 1 = bf16, 0 = f32
}

// A [k][v][w] -> At3[w][vc][16] f32 (64B-aligned 15-coeff segments, slot15=0)
//             + cs4[w][4]: cs4[w*4+k] = sum_v A[k][v][w]
__global__ __launch_bounds__(256) void k_convA(const void* __restrict__ src,
                                               float* __restrict__ At3,
                                               float* __restrict__ cs4,
                                               const int* __restrict__ flag)
{
    const bool isbf = (*flag != 0);
    const int tid = threadIdx.x;
    __shared__ float As[1875];
    for (int i = tid; i < 1875; i += 256)
        As[i] = isbf ? bf2f(((const ush*)src)[i]) : ((const float*)src)[i];
    __syncthreads();
    // At3[(w*5+vc)*16 + v5*3 + k] = A[k][vc*5+v5][w]
    for (int j = tid; j < 2000; j += 256) {
        int w = j / 80, r = j - w * 80, vc = r >> 4, s = r & 15;
        float val = 0.f;
        if (s < 15) {
            int v5 = s / 3, k = s - v5 * 3;
            val = As[k * 625 + (vc * 5 + v5) * 25 + w];
        }
        At3[j] = val;
    }
    for (int j = tid; j < 100; j += 256) {
        int w = j >> 2, k = j & 3;
        float s = 0.f;
        if (k < 3)
            for (int v = 0; v < NV; ++v) s += As[k * 625 + v * 25 + w];
        cs4[j] = s;
    }
}

// -------- single-launch converter: plain copies + [K,N]->[N,K] transposes --------
struct CvEnt { const void* src; ush* dst; int n; int K; int N; int blk0; };
struct CvTab { CvEnt e[16]; };

__global__ __launch_bounds__(256) void k_convall(CvTab tab, const int* __restrict__ flag)
{
    const bool isbf = (*flag != 0);
    const int bi = (int)blockIdx.x;
    int ei = 0;
    #pragma unroll
    for (int i = 1; i < 16; ++i) if (bi >= tab.e[i].blk0) ei = i;
    const CvEnt& e = tab.e[ei];
    const int idx = (bi - e.blk0) * 256 + (int)threadIdx.x;
    if (idx >= e.n) return;
    int s;
    if (e.K == 0) s = idx;
    else { int n = idx / e.K, k = idx - n * e.K; s = k * e.N + n; }
    e.dst[idx] = isbf ? ((const ush*)e.src)[s] : f2bf(((const float*)e.src)[s]);
}

// -------- MFMA GEMM: C[M, cols n0..] = A[M,K] @ Bt[N,K]^T --------
__global__ __launch_bounds__(256) void k_gemm(
    const ush* __restrict__ A, const ush* __restrict__ Bt, ush* __restrict__ C,
    int M, int K, int ldC)
{
    const int n0 = blockIdx.x * 128, m0 = blockIdx.y * 128;
    const int tid = threadIdx.x, w = tid >> 6, l = tid & 63;
    __shared__ ush As[8192], Bs[8192];   // 16KB each: 128 rows x 128B, linear
    const char* AsB = (const char*)As;
    const char* BsB = (const char*)Bs;
    const int rl = l >> 3, cc = l & 7;
    f4v acc[4][4] = {};
    const int wm = w >> 1, wn = w & 1;

    for (int kt = 0; kt < K; kt += 64) {
        __syncthreads();
        #pragma unroll
        for (int j = 0; j < 4; ++j) {
            const int r = (w * 4 + j) * 8 + rl;
            const int sc = (cc ^ (r & 7)) * 8;
            const ush* ga = &A[(size_t)(m0 + r) * K + kt + sc];
            const ush* gb = &Bt[(size_t)(n0 + r) * K + kt + sc];
            __builtin_amdgcn_global_load_lds(
                (const __attribute__((address_space(1))) uint32*)ga,
                (__attribute__((address_space(3))) uint32*)&As[(w * 4 + j) * 512], 16, 0, 0);
            __builtin_amdgcn_global_load_lds(
                (const __attribute__((address_space(1))) uint32*)gb,
                (__attribute__((address_space(3))) uint32*)&Bs[(w * 4 + j) * 512], 16, 0, 0);
        }
        __syncthreads();
        #pragma unroll
        for (int ks = 0; ks < 2; ++ks) {
            const int ko = ks * 64 + (l >> 4) * 16;
            s8v a[4], b[4];
            #pragma unroll
            for (int mi = 0; mi < 4; ++mi) {
                const int ra = wm * 64 + mi * 16 + (l & 15);
                a[mi] = *(const s8v*)(AsB + ra * 128 + (ko ^ ((ra & 7) << 4)));
            }
            #pragma unroll
            for (int ni = 0; ni < 4; ++ni) {
                const int rb = wn * 64 + ni * 16 + (l & 15);
                b[ni] = *(const s8v*)(BsB + rb * 128 + (ko ^ ((rb & 7) << 4)));
            }
            #pragma unroll
            for (int mi = 0; mi < 4; ++mi)
                #pragma unroll
                for (int ni = 0; ni < 4; ++ni)
                    acc[mi][ni] = __builtin_amdgcn_mfma_f32_16x16x32_bf16(a[mi], b[ni],
                                                                          acc[mi][ni], 0, 0, 0);
        }
    }
    const int col = n0 + wn * 64 + (l & 15);
    #pragma unroll
    for (int mi = 0; mi < 4; ++mi) {
        const int row_base = m0 + wm * 64 + mi * 16 + (l >> 4) * 4;
        #pragma unroll
        for (int ni = 0; ni < 4; ++ni)
            #pragma unroll
            for (int r = 0; r < 4; ++r)
                C[(size_t)(row_base + r) * ldC + col + ni * 16] = f2bf(acc[mi][ni][r]);
    }
}

// -------- MFMA attention: 1 wave = 1 (b,h,v) head; zero LDS --------
template<int MASKED>
__global__ __launch_bounds__(64) void k_attn_mfma(
    const ush* __restrict__ QKV, ush* __restrict__ O)
{
    const int v = blockIdx.x, h = blockIdx.y, b = blockIdx.z;
    const int l = threadIdx.x, g = l >> 4, c = l & 15;
    const size_t tokStride = (size_t)NV * NKC;
    const ush* base = QKV + ((size_t)b * NT * NV + v) * NKC;

    s8v kf[8];
    const int koff = 256 + h * ND + g * 8;
    #pragma unroll
    for (int si = 0; si < 8; ++si)
        kf[si] = *(const s8v*)(base + (size_t)(16 * si + c) * tokStride + koff);

    s8v vf[4][2];
    #pragma unroll
    for (int ks = 0; ks < 4; ++ks)
        #pragma unroll
        for (int ni = 0; ni < 2; ++ni) {
            const int voff = 512 + h * ND + 16 * ni + c;
            s8v tmp;
            #pragma unroll
            for (int j = 0; j < 8; ++j)
                tmp[j] = (short)base[(size_t)(32 * ks + 8 * g + j) * tokStride + voff];
            vf[ks][ni] = tmp;
        }

    ush* og = O + ((size_t)b * NT * NV + v) * NC + h * ND;
    const int qoff = h * ND + g * 8;
    const int ga = (g & 1) * 2;
    const int l1 = ga * 16 + c, l2 = l1 + 16;
    const bool hisel = (g >> 1) != 0;

    for (int t16 = 0; t16 < 8; ++t16) {
        s8v qf = *(const s8v*)(base + (size_t)(16 * t16 + c) * tokStride + qoff);
        f4v st[8];
        #pragma unroll
        for (int si = 0; si < 8; ++si)
            st[si] = __builtin_amdgcn_mfma_f32_16x16x32_bf16(kf[si], qf,
                                                             (f4v){0.f, 0.f, 0.f, 0.f}, 0, 0, 0);
        const int t = 16 * t16 + c;
        if (MASKED) {
            #pragma unroll
            for (int si = 0; si < 8; ++si)
                #pragma unroll
                for (int r = 0; r < 4; ++r)
                    if (16 * si + 4 * g + r > t) st[si][r] = -1e30f;
        }
        float mx = -1e30f;
        #pragma unroll
        for (int si = 0; si < 8; ++si)
            #pragma unroll
            for (int r = 0; r < 4; ++r) mx = fmaxf(mx, st[si][r]);
        mx = fmaxf(mx, __shfl_xor(mx, 16));
        mx = fmaxf(mx, __shfl_xor(mx, 32));
        float sm = 0.f;
        #pragma unroll
        for (int si = 0; si < 8; ++si)
            #pragma unroll
            for (int r = 0; r < 4; ++r) {
                float e = __expf((st[si][r] - mx) * QSCALE);
                st[si][r] = e;
                sm += e;
            }
        sm += __shfl_xor(sm, 16);
        sm += __shfl_xor(sm, 32);
        const float inv = 1.f / sm;
        uint32 u[8][2];
        #pragma unroll
        for (int si = 0; si < 8; ++si) {
            float e0 = st[si][0] * inv, e1 = st[si][1] * inv;
            float e2 = st[si][2] * inv, e3 = st[si][3] * inv;
            asm("v_cvt_pk_bf16_f32 %0, %1, %2" : "=v"(u[si][0]) : "v"(e0), "v"(e1));
            asm("v_cvt_pk_bf16_f32 %0, %1, %2" : "=v"(u[si][1]) : "v"(e2), "v"(e3));
        }
        f4v o[2] = {};
        #pragma unroll
        for (int ks = 0; ks < 4; ++ks) {
            uint32 w0a = __shfl(u[2 * ks][0], l1),     w0b = __shfl(u[2 * ks][1], l1);
            uint32 w0c = __shfl(u[2 * ks][0], l2),     w0d = __shfl(u[2 * ks][1], l2);
            uint32 w1a = __shfl(u[2 * ks + 1][0], l1), w1b = __shfl(u[2 * ks + 1][1], l1);
            uint32 w1c = __shfl(u[2 * ks + 1][0], l2), w1d = __shfl(u[2 * ks + 1][1], l2);
            union { uint32 w[4]; s8v s; } pa;
            pa.w[0] = hisel ? w1a : w0a;
            pa.w[1] = hisel ? w1b : w0b;
            pa.w[2] = hisel ? w1c : w0c;
            pa.w[3] = hisel ? w1d : w0d;
            o[0] = __builtin_amdgcn_mfma_f32_16x16x32_bf16(pa.s, vf[ks][0], o[0], 0, 0, 0);
            o[1] = __builtin_amdgcn_mfma_f32_16x16x32_bf16(pa.s, vf[ks][1], o[1], 0, 0, 0);
        }
        #pragma unroll
        for (int ni = 0; ni < 2; ++ni)
            #pragma unroll
            for (int r = 0; r < 4; ++r)
                og[(size_t)(16 * t16 + 4 * g + r) * (NV * NC) + 16 * ni + c] = f2bf(o[ni][r]);
    }
}

// ---------------- row LayerNorm (unbiased std), in place, 1 wave = 1 row ----------------
__global__ __launch_bounds__(256) void k_ln(
    ush* __restrict__ buf, const ush* __restrict__ g, const ush* __restrict__ bb)
{
    const int row = blockIdx.x * 4 + (threadIdx.x >> 6);
    const int lane = threadIdx.x & 63;
    ush* p = buf + (size_t)row * NC + lane * 4;
    uint2 u = *(uint2*)p;
    float x0 = bf2f((ush)(u.x & 0xffff)), x1 = bf2f((ush)(u.x >> 16));
    float x2 = bf2f((ush)(u.y & 0xffff)), x3 = bf2f((ush)(u.y >> 16));
    float s = x0 + x1 + x2 + x3;
    float q = x0 * x0 + x1 * x1 + x2 * x2 + x3 * x3;
    #pragma unroll
    for (int o = 32; o; o >>= 1) { s += __shfl_xor(s, o); q += __shfl_xor(q, o); }
    float mean = s * (1.f / 256.f);
    float var = fmaxf((q - 256.f * mean * mean) * (1.f / 255.f), 0.f);
    float inv = 1.f / (sqrtf(var) + LN_EPS);
    float o0 = bf2f(g[lane * 4 + 0]) * (x0 - mean) * inv + bf2f(bb[lane * 4 + 0]);
    float o1 = bf2f(g[lane * 4 + 1]) * (x1 - mean) * inv + bf2f(bb[lane * 4 + 1]);
    float o2 = bf2f(g[lane * 4 + 2]) * (x2 - mean) * inv + bf2f(bb[lane * 4 + 2]);
    float o3 = bf2f(g[lane * 4 + 3]) * (x3 - mean) * inv + bf2f(bb[lane * 4 + 3]);
    uint32 lo = (uint32)f2bf(o0) | ((uint32)f2bf(o1) << 16);
    uint32 hi = (uint32)f2bf(o2) | ((uint32)f2bf(o3) << 16);
    *(uint2*)p = make_uint2(lo, hi);
}

// -------- GCN contraction + bias + LayerNorm; streamed v-chunks --------
// 5 chunks x 5 v: chunk i+1's 15 coalesced loads overlap chunk i's 375 FMAs.
// At3[w][vc][16] f32, 64B-aligned -> one s_load_dwordx16 per (w,chunk).
__global__ __launch_bounds__(256) void k_gcn(
    const ush* __restrict__ xw, const float* __restrict__ At3,
    const float* __restrict__ cs4,
    const ush* __restrict__ bg, const ush* __restrict__ g3, const ush* __restrict__ b3,
    float* __restrict__ outp)
{
    const int t = blockIdx.x, b = blockIdx.y;
    const int tid = threadIdx.x;
    __shared__ float h3s[NV * NC];   // 25.6KB

    const ush* xr = xw + ((size_t)(b * NT + t)) * NV * NKC + tid;
    float bgv[3];
    #pragma unroll
    for (int k = 0; k < NK; ++k) bgv[k] = bf2f(bg[k * NC + tid]);

    float acc[NV];
    #pragma unroll
    for (int w = 0; w < NV; ++w)
        acc[w] = bgv[0] * cs4[w * 4] + bgv[1] * cs4[w * 4 + 1] + bgv[2] * cs4[w * 4 + 2];

    float xc[15], xn[15];
    #pragma unroll
    for (int j = 0; j < 15; ++j) {           // chunk 0: v=0..4
        int v5 = j / 3, k = j - v5 * 3;
        xc[j] = bf2f(xr[(size_t)v5 * NKC + k * NC]);
    }
    #pragma unroll
    for (int vc = 0; vc < 5; ++vc) {
        if (vc < 4) {
            #pragma unroll
            for (int j = 0; j < 15; ++j) {   // prefetch next chunk
                int v5 = j / 3, k = j - v5 * 3;
                xn[j] = bf2f(xr[(size_t)((vc + 1) * 5 + v5) * NKC + k * NC]);
            }
        }
        #pragma unroll
        for (int w = 0; w < NV; ++w) {
            const float* a = At3 + (w * 5 + vc) * 16;   // uniform -> s_load_dwordx16
            float s0 = a[0] * xc[0] + a[3] * xc[3] + a[6] * xc[6] + a[9] * xc[9] + a[12] * xc[12];
            float s1 = a[1] * xc[1] + a[4] * xc[4] + a[7] * xc[7] + a[10] * xc[10] + a[13] * xc[13];
            float s2 = a[2] * xc[2] + a[5] * xc[5] + a[8] * xc[8] + a[11] * xc[11] + a[14] * xc[14];
            acc[w] += s0 + s1 + s2;
        }
        #pragma unroll
        for (int j = 0; j < 15; ++j) xc[j] = xn[j];
    }
    #pragma unroll
    for (int w = 0; w < NV; ++w) h3s[w * NC + tid] = acc[w];
    __syncthreads();
    {
        const int wv = tid >> 6, lane = tid & 63;
        for (int w = wv; w < NV; w += 4) {
            float4 xq = *(const float4*)&h3s[w * NC + lane * 4];
            float s = xq.x + xq.y + xq.z + xq.w;
            float q = xq.x * xq.x + xq.y * xq.y + xq.z * xq.z + xq.w * xq.w;
            #pragma unroll
            for (int o = 32; o; o >>= 1) { s += __shfl_xor(s, o); q += __shfl_xor(q, o); }
            float mean = s * (1.f / 256.f);
            float var = fmaxf((q - 256.f * mean * mean) * (1.f / 255.f), 0.f);
            float inv = 1.f / (sqrtf(var) + LN_EPS);
            float o0 = bf2f(g3[lane * 4 + 0]) * (xq.x - mean) * inv + bf2f(b3[lane * 4 + 0]);
            float o1 = bf2f(g3[lane * 4 + 1]) * (xq.y - mean) * inv + bf2f(b3[lane * 4 + 1]);
            float o2 = bf2f(g3[lane * 4 + 2]) * (xq.z - mean) * inv + bf2f(b3[lane * 4 + 2]);
            float o3 = bf2f(g3[lane * 4 + 3]) * (xq.w - mean) * inv + bf2f(b3[lane * 4 + 3]);
            float* op = outp + (((size_t)(b * NT + t)) * NV + w) * NC + lane * 4;
            *(float4*)op = make_float4(o0, o1, o2, o3);
        }
    }
}

extern "C" void kernel_launch(void* const* d_in, const int* in_sizes, int n_in,
                              void* d_out, int out_size, void* d_ws, size_t ws_size,
                              hipStream_t stream)
{
    const size_t NTOK = (size_t)NB * NT * NV;   // 51200
    char* ws = (char*)d_ws;
    int* flag = (int*)ws;
    float* At3 = (float*)(ws + 256);            // [25][5][16] f32, 8KB
    float* cs4 = (float*)(ws + 256 + 8000);     // [25][4] f32, 400B
    ush* bufA = (ush*)(ws + 16384);             // [M,768]  78.6MB
    ush* bufB = bufA + NTOK * NKC;              // [M,256]  26.2MB
    ush* conv = bufB + NTOK * NC;

    k_detect<<<1, 256, 0, stream>>>((const uint32*)d_in[0], flag);
    k_convA<<<1, 256, 0, stream>>>(d_in[2], At3, cs4, flag);

    // ---- one-launch conversion table ----
    CvTab tab;
    int nent = 0, blk = 0;
    ush* p = conv;
    const ush* cp[18] = {};
    auto add = [&](int idx, int n, int K, int N, ush*& dst_out) {
        tab.e[nent] = { d_in[idx], p, n, K, N, blk };
        dst_out = p;
        blk += (n + 255) / 256;
        p += (size_t)((n + 7) & ~7);
        ++nent;
    };
    ush* d;
    add(0, NB * NT * NV * NCIN, 0, 0, d);  cp[0] = d;
    add(1, NB * NTM * NV * NCM, 0, 0, d);  cp[1] = d;
    add(15, NKC, 0, 0, d);                 cp[15] = d;
    add(7, NC, 0, 0, d);  cp[7] = d;
    add(8, NC, 0, 0, d);  cp[8] = d;
    add(12, NC, 0, 0, d); cp[12] = d;
    add(13, NC, 0, 0, d); cp[13] = d;
    add(16, NC, 0, 0, d); cp[16] = d;
    add(17, NC, 0, 0, d); cp[17] = d;
    ush* w1t;
    add(4, NCIN * NC, NCIN, NC, w1t);      // [256][64] q
    add(5, NCIN * NC, NCIN, NC, d);        // k  (contiguous after q)
    add(6, NCIN * NC, NCIN, NC, d);        // v
    ush* wq2t;
    add(9, NC * NC, NC, NC, wq2t);         // [256][256]
    ush* wkv2t;
    add(10, NCM * NC, NCM, NC, wkv2t);     // [256][256] k
    add(11, NCM * NC, NCM, NC, d);         // v (contiguous)
    ush* wgt;
    add(14, NC * NKC, NC, NKC, wgt);       // [768][256]
    k_convall<<<blk, 256, 0, stream>>>(tab, flag);

    const int M = (int)NTOK;
    // stage 1: qkv1 = x @ [Wq1|Wk1|Wv1]  -> bufA [M,768]
    k_gemm<<<dim3(6, M / 128), 256, 0, stream>>>(cp[0], w1t, bufA, M, NCIN, NKC);
    k_attn_mfma<1><<<dim3(NV, NH, NB), 64, 0, stream>>>(bufA, bufB);
    k_ln<<<M / 4, 256, 0, stream>>>(bufB, cp[7], cp[8]);
    // stage 2: q2 = h1 @ Wq2 (cols 0-255); kv2 = m @ [Wk2|Wv2] (cols 256-767)
    k_gemm<<<dim3(2, M / 128), 256, 0, stream>>>(bufB, wq2t, bufA, M, NC, NKC);
    k_gemm<<<dim3(4, M / 128), 256, 0, stream>>>(cp[1], wkv2t, bufA + 256, M, NCM, NKC);
    k_attn_mfma<0><<<dim3(NV, NH, NB), 64, 0, stream>>>(bufA, bufB);
    k_ln<<<M / 4, 256, 0, stream>>>(bufB, cp[12], cp[13]);
    // stage 3: xw = h2 @ Wg -> bufA [M,768]; then GCN+LN -> out
    k_gemm<<<dim3(6, M / 128), 256, 0, stream>>>(bufB, wgt, bufA, M, NC, NKC);
    k_gcn<<<dim3(NT, NB), 256, 0, stream>>>(bufA, At3, cs4, cp[15], cp[16], cp[17],
                                            (float*)d_out);
}

// Round 11
// 300.849 us; speedup vs baseline: 1.2476x; 1.1042x over previous
//
#include <hip/hip_runtime.h>
#include <hip/hip_bf16.h>

typedef unsigned short ush;
typedef unsigned int uint32;
typedef __attribute__((ext_vector_type(8))) short s8v;   // 8 bf16 (4 VGPRs)
typedef __attribute__((ext_vector_type(4))) float f4v;   // MFMA accumulator

#define NB 16
#define NT 128
#define NTM 128
#define NV 25
#define NCIN 64
#define NCM 256
#define NH 8
#define ND 32
#define NC 256
#define NK 3
#define NKC 768
#define LN_EPS 1e-6f
#define QSCALE 0.17677669529663687f

__device__ __forceinline__ float bf2f(ush u) {
    union { uint32 i; float f; } x; x.i = ((uint32)u) << 16; return x.f;
}
__device__ __forceinline__ ush f2bf(float f) {
    union { float f; uint32 i; } x; x.f = f;
    uint32 r = x.i + 0x7FFFu + ((x.i >> 16) & 1u);
    return (ush)(r >> 16);
}
__device__ __forceinline__ uint32 pack2(float a, float b) {
    return (uint32)f2bf(a) | ((uint32)f2bf(b) << 16);
}

// -------- dtype detector (f32 vs bf16 device buffers) --------
__global__ __launch_bounds__(256) void k_detect(const uint32* __restrict__ xw,
                                               int* __restrict__ flag)
{
    __shared__ int cnt;
    if (threadIdx.x == 0) cnt = 0;
    __syncthreads();
    int c = 0;
    for (int i = 0; i < 4; ++i) {
        uint32 u = xw[threadIdx.x + 256 * i];
        uint32 e = (u >> 7) & 0xFF;
        c += (e >= 100 && e <= 135) ? 1 : 0;
    }
    atomicAdd(&cnt, c);
    __syncthreads();
    if (threadIdx.x == 0) *flag = (cnt > 700) ? 1 : 0;   // 1 = bf16, 0 = f32
}

// A [k][v][w] -> At3[w][vc][16] f32 (64B-aligned 15-coeff segments, slot15=0)
//             + cs4[w][4]: cs4[w*4+k] = sum_v A[k][v][w]
__global__ __launch_bounds__(256) void k_convA(const void* __restrict__ src,
                                               float* __restrict__ At3,
                                               float* __restrict__ cs4,
                                               const int* __restrict__ flag)
{
    const bool isbf = (*flag != 0);
    const int tid = threadIdx.x;
    __shared__ float As[1875];
    for (int i = tid; i < 1875; i += 256)
        As[i] = isbf ? bf2f(((const ush*)src)[i]) : ((const float*)src)[i];
    __syncthreads();
    for (int j = tid; j < 2000; j += 256) {
        int w = j / 80, r = j - w * 80, vc = r >> 4, s = r & 15;
        float val = 0.f;
        if (s < 15) {
            int v5 = s / 3, k = s - v5 * 3;
            val = As[k * 625 + (vc * 5 + v5) * 25 + w];
        }
        At3[j] = val;
    }
    for (int j = tid; j < 100; j += 256) {
        int w = j >> 2, k = j & 3;
        float s = 0.f;
        if (k < 3)
            for (int v = 0; v < NV; ++v) s += As[k * 625 + v * 25 + w];
        cs4[j] = s;
    }
}

// -------- single-launch converter --------
// K==0: plain copy, 8 elems/thread (uint4 loads/stores, n % 8 == 0).
// K!=0: [K,N]->[N,K] transpose; iterate SOURCE linearly (coalesced reads,
//       scattered 2B writes), 4 elems/thread (n % 4 == 0).
struct CvEnt { const void* src; ush* dst; int n; int K; int N; int blk0; };
struct CvTab { CvEnt e[16]; };

__global__ __launch_bounds__(256) void k_convall(CvTab tab, const int* __restrict__ flag)
{
    const bool isbf = (*flag != 0);
    const int bi = (int)blockIdx.x;
    int ei = 0;
    #pragma unroll
    for (int i = 1; i < 16; ++i) if (bi >= tab.e[i].blk0) ei = i;
    const CvEnt& e = tab.e[ei];
    if (e.K == 0) {
        const int idx = (bi - e.blk0) * 2048 + (int)threadIdx.x * 8;
        if (idx >= e.n) return;
        if (isbf) {
            *(uint4*)&e.dst[idx] = *(const uint4*)((const ush*)e.src + idx);
        } else {
            const float* s = (const float*)e.src + idx;
            uint4 a = *(const uint4*)s;
            uint4 b = *(const uint4*)(s + 4);
            uint4 o;
            o.x = pack2(((float*)&a)[0], ((float*)&a)[1]);
            o.y = pack2(((float*)&a)[2], ((float*)&a)[3]);
            o.z = pack2(((float*)&b)[0], ((float*)&b)[1]);
            o.w = pack2(((float*)&b)[2], ((float*)&b)[3]);
            *(uint4*)&e.dst[idx] = o;
        }
    } else {
        const int s4 = (bi - e.blk0) * 1024 + (int)threadIdx.x * 4;  // source index
        if (s4 >= e.n) return;
        const int k = s4 / e.N, n0 = s4 - k * e.N;   // src [K][N], 4 consecutive n
        float v0, v1, v2, v3;
        if (isbf) {
            const ush* s = (const ush*)e.src + s4;
            v0 = bf2f(s[0]); v1 = bf2f(s[1]); v2 = bf2f(s[2]); v3 = bf2f(s[3]);
        } else {
            float4 f = *(const float4*)((const float*)e.src + s4);
            v0 = f.x; v1 = f.y; v2 = f.z; v3 = f.w;
        }
        ush* d = e.dst + (size_t)n0 * e.K + k;        // dst [N][K], stride K
        d[0] = f2bf(v0);
        d[e.K] = f2bf(v1);
        d[2 * e.K] = f2bf(v2);
        d[3 * e.K] = f2bf(v3);
    }
}

// -------- MFMA GEMM: C[M, cols n0..] = A[M,K] @ Bt[N,K]^T --------
__global__ __launch_bounds__(256) void k_gemm(
    const ush* __restrict__ A, const ush* __restrict__ Bt, ush* __restrict__ C,
    int M, int K, int ldC)
{
    const int n0 = blockIdx.x * 128, m0 = blockIdx.y * 128;
    const int tid = threadIdx.x, w = tid >> 6, l = tid & 63;
    __shared__ ush As[8192], Bs[8192];   // 16KB each: 128 rows x 128B, linear
    const char* AsB = (const char*)As;
    const char* BsB = (const char*)Bs;
    const int rl = l >> 3, cc = l & 7;
    f4v acc[4][4] = {};
    const int wm = w >> 1, wn = w & 1;

    for (int kt = 0; kt < K; kt += 64) {
        __syncthreads();
        #pragma unroll
        for (int j = 0; j < 4; ++j) {
            const int r = (w * 4 + j) * 8 + rl;
            const int sc = (cc ^ (r & 7)) * 8;
            const ush* ga = &A[(size_t)(m0 + r) * K + kt + sc];
            const ush* gb = &Bt[(size_t)(n0 + r) * K + kt + sc];
            __builtin_amdgcn_global_load_lds(
                (const __attribute__((address_space(1))) uint32*)ga,
                (__attribute__((address_space(3))) uint32*)&As[(w * 4 + j) * 512], 16, 0, 0);
            __builtin_amdgcn_global_load_lds(
                (const __attribute__((address_space(1))) uint32*)gb,
                (__attribute__((address_space(3))) uint32*)&Bs[(w * 4 + j) * 512], 16, 0, 0);
        }
        __syncthreads();
        #pragma unroll
        for (int ks = 0; ks < 2; ++ks) {
            const int ko = ks * 64 + (l >> 4) * 16;
            s8v a[4], b[4];
            #pragma unroll
            for (int mi = 0; mi < 4; ++mi) {
                const int ra = wm * 64 + mi * 16 + (l & 15);
                a[mi] = *(const s8v*)(AsB + ra * 128 + (ko ^ ((ra & 7) << 4)));
            }
            #pragma unroll
            for (int ni = 0; ni < 4; ++ni) {
                const int rb = wn * 64 + ni * 16 + (l & 15);
                b[ni] = *(const s8v*)(BsB + rb * 128 + (ko ^ ((rb & 7) << 4)));
            }
            #pragma unroll
            for (int mi = 0; mi < 4; ++mi)
                #pragma unroll
                for (int ni = 0; ni < 4; ++ni)
                    acc[mi][ni] = __builtin_amdgcn_mfma_f32_16x16x32_bf16(a[mi], b[ni],
                                                                          acc[mi][ni], 0, 0, 0);
        }
    }
    const int col = n0 + wn * 64 + (l & 15);
    #pragma unroll
    for (int mi = 0; mi < 4; ++mi) {
        const int row_base = m0 + wm * 64 + mi * 16 + (l >> 4) * 4;
        #pragma unroll
        for (int ni = 0; ni < 4; ++ni)
            #pragma unroll
            for (int r = 0; r < 4; ++r)
                C[(size_t)(row_base + r) * ldC + col + ni * 16] = f2bf(acc[mi][ni][r]);
    }
}

// -------- MFMA attention: 1 wave = 1 (b,h,v) head; zero LDS --------
template<int MASKED>
__global__ __launch_bounds__(64) void k_attn_mfma(
    const ush* __restrict__ QKV, ush* __restrict__ O)
{
    const int v = blockIdx.x, h = blockIdx.y, b = blockIdx.z;
    const int l = threadIdx.x, g = l >> 4, c = l & 15;
    const size_t tokStride = (size_t)NV * NKC;
    const ush* base = QKV + ((size_t)b * NT * NV + v) * NKC;

    s8v kf[8];
    const int koff = 256 + h * ND + g * 8;
    #pragma unroll
    for (int si = 0; si < 8; ++si)
        kf[si] = *(const s8v*)(base + (size_t)(16 * si + c) * tokStride + koff);

    s8v vf[4][2];
    #pragma unroll
    for (int ks = 0; ks < 4; ++ks)
        #pragma unroll
        for (int ni = 0; ni < 2; ++ni) {
            const int voff = 512 + h * ND + 16 * ni + c;
            s8v tmp;
            #pragma unroll
            for (int j = 0; j < 8; ++j)
                tmp[j] = (short)base[(size_t)(32 * ks + 8 * g + j) * tokStride + voff];
            vf[ks][ni] = tmp;
        }

    ush* og = O + ((size_t)b * NT * NV + v) * NC + h * ND;
    const int qoff = h * ND + g * 8;
    const int ga = (g & 1) * 2;
    const int l1 = ga * 16 + c, l2 = l1 + 16;
    const bool hisel = (g >> 1) != 0;

    for (int t16 = 0; t16 < 8; ++t16) {
        s8v qf = *(const s8v*)(base + (size_t)(16 * t16 + c) * tokStride + qoff);
        f4v st[8];
        #pragma unroll
        for (int si = 0; si < 8; ++si)
            st[si] = __builtin_amdgcn_mfma_f32_16x16x32_bf16(kf[si], qf,
                                                             (f4v){0.f, 0.f, 0.f, 0.f}, 0, 0, 0);
        const int t = 16 * t16 + c;
        if (MASKED) {
            #pragma unroll
            for (int si = 0; si < 8; ++si)
                #pragma unroll
                for (int r = 0; r < 4; ++r)
                    if (16 * si + 4 * g + r > t) st[si][r] = -1e30f;
        }
        float mx = -1e30f;
        #pragma unroll
        for (int si = 0; si < 8; ++si)
            #pragma unroll
            for (int r = 0; r < 4; ++r) mx = fmaxf(mx, st[si][r]);
        mx = fmaxf(mx, __shfl_xor(mx, 16));
        mx = fmaxf(mx, __shfl_xor(mx, 32));
        float sm = 0.f;
        #pragma unroll
        for (int si = 0; si < 8; ++si)
            #pragma unroll
            for (int r = 0; r < 4; ++r) {
                float e = __expf((st[si][r] - mx) * QSCALE);
                st[si][r] = e;
                sm += e;
            }
        sm += __shfl_xor(sm, 16);
        sm += __shfl_xor(sm, 32);
        const float inv = 1.f / sm;
        uint32 u[8][2];
        #pragma unroll
        for (int si = 0; si < 8; ++si) {
            float e0 = st[si][0] * inv, e1 = st[si][1] * inv;
            float e2 = st[si][2] * inv, e3 = st[si][3] * inv;
            asm("v_cvt_pk_bf16_f32 %0, %1, %2" : "=v"(u[si][0]) : "v"(e0), "v"(e1));
            asm("v_cvt_pk_bf16_f32 %0, %1, %2" : "=v"(u[si][1]) : "v"(e2), "v"(e3));
        }
        f4v o[2] = {};
        #pragma unroll
        for (int ks = 0; ks < 4; ++ks) {
            uint32 w0a = __shfl(u[2 * ks][0], l1),     w0b = __shfl(u[2 * ks][1], l1);
            uint32 w0c = __shfl(u[2 * ks][0], l2),     w0d = __shfl(u[2 * ks][1], l2);
            uint32 w1a = __shfl(u[2 * ks + 1][0], l1), w1b = __shfl(u[2 * ks + 1][1], l1);
            uint32 w1c = __shfl(u[2 * ks + 1][0], l2), w1d = __shfl(u[2 * ks + 1][1], l2);
            union { uint32 w[4]; s8v s; } pa;
            pa.w[0] = hisel ? w1a : w0a;
            pa.w[1] = hisel ? w1b : w0b;
            pa.w[2] = hisel ? w1c : w0c;
            pa.w[3] = hisel ? w1d : w0d;
            o[0] = __builtin_amdgcn_mfma_f32_16x16x32_bf16(pa.s, vf[ks][0], o[0], 0, 0, 0);
            o[1] = __builtin_amdgcn_mfma_f32_16x16x32_bf16(pa.s, vf[ks][1], o[1], 0, 0, 0);
        }
        #pragma unroll
        for (int ni = 0; ni < 2; ++ni)
            #pragma unroll
            for (int r = 0; r < 4; ++r)
                og[(size_t)(16 * t16 + 4 * g + r) * (NV * NC) + 16 * ni + c] = f2bf(o[ni][r]);
    }
}

// ---------------- row LayerNorm (unbiased std), in place, 1 wave = 1 row ----------------
__global__ __launch_bounds__(256) void k_ln(
    ush* __restrict__ buf, const ush* __restrict__ g, const ush* __restrict__ bb)
{
    const int row = blockIdx.x * 4 + (threadIdx.x >> 6);
    const int lane = threadIdx.x & 63;
    ush* p = buf + (size_t)row * NC + lane * 4;
    uint2 u = *(uint2*)p;
    float x0 = bf2f((ush)(u.x & 0xffff)), x1 = bf2f((ush)(u.x >> 16));
    float x2 = bf2f((ush)(u.y & 0xffff)), x3 = bf2f((ush)(u.y >> 16));
    float s = x0 + x1 + x2 + x3;
    float q = x0 * x0 + x1 * x1 + x2 * x2 + x3 * x3;
    #pragma unroll
    for (int o = 32; o; o >>= 1) { s += __shfl_xor(s, o); q += __shfl_xor(q, o); }
    float mean = s * (1.f / 256.f);
    float var = fmaxf((q - 256.f * mean * mean) * (1.f / 255.f), 0.f);
    float inv = 1.f / (sqrtf(var) + LN_EPS);
    float o0 = bf2f(g[lane * 4 + 0]) * (x0 - mean) * inv + bf2f(bb[lane * 4 + 0]);
    float o1 = bf2f(g[lane * 4 + 1]) * (x1 - mean) * inv + bf2f(bb[lane * 4 + 1]);
    float o2 = bf2f(g[lane * 4 + 2]) * (x2 - mean) * inv + bf2f(bb[lane * 4 + 2]);
    float o3 = bf2f(g[lane * 4 + 3]) * (x3 - mean) * inv + bf2f(bb[lane * 4 + 3]);
    uint32 lo = (uint32)f2bf(o0) | ((uint32)f2bf(o1) << 16);
    uint32 hi = (uint32)f2bf(o2) | ((uint32)f2bf(o3) << 16);
    *(uint2*)p = make_uint2(lo, hi);
}

// -------- GCN contraction + bias + LayerNorm; streamed v-chunks --------
__global__ __launch_bounds__(256) void k_gcn(
    const ush* __restrict__ xw, const float* __restrict__ At3,
    const float* __restrict__ cs4,
    const ush* __restrict__ bg, const ush* __restrict__ g3, const ush* __restrict__ b3,
    float* __restrict__ outp)
{
    const int t = blockIdx.x, b = blockIdx.y;
    const int tid = threadIdx.x;
    __shared__ float h3s[NV * NC];   // 25.6KB

    const ush* xr = xw + ((size_t)(b * NT + t)) * NV * NKC + tid;
    float bgv[3];
    #pragma unroll
    for (int k = 0; k < NK; ++k) bgv[k] = bf2f(bg[k * NC + tid]);

    float acc[NV];
    #pragma unroll
    for (int w = 0; w < NV; ++w)
        acc[w] = bgv[0] * cs4[w * 4] + bgv[1] * cs4[w * 4 + 1] + bgv[2] * cs4[w * 4 + 2];

    float xc[15], xn[15];
    #pragma unroll
    for (int j = 0; j < 15; ++j) {           // chunk 0: v=0..4
        int v5 = j / 3, k = j - v5 * 3;
        xc[j] = bf2f(xr[(size_t)v5 * NKC + k * NC]);
    }
    #pragma unroll
    for (int vc = 0; vc < 5; ++vc) {
        if (vc < 4) {
            #pragma unroll
            for (int j = 0; j < 15; ++j) {   // prefetch next chunk
                int v5 = j / 3, k = j - v5 * 3;
                xn[j] = bf2f(xr[(size_t)((vc + 1) * 5 + v5) * NKC + k * NC]);
            }
        }
        #pragma unroll
        for (int w = 0; w < NV; ++w) {
            const float* a = At3 + (w * 5 + vc) * 16;   // uniform -> s_load_dwordx16
            float s0 = a[0] * xc[0] + a[3] * xc[3] + a[6] * xc[6] + a[9] * xc[9] + a[12] * xc[12];
            float s1 = a[1] * xc[1] + a[4] * xc[4] + a[7] * xc[7] + a[10] * xc[10] + a[13] * xc[13];
            float s2 = a[2] * xc[2] + a[5] * xc[5] + a[8] * xc[8] + a[11] * xc[11] + a[14] * xc[14];
            acc[w] += s0 + s1 + s2;
        }
        #pragma unroll
        for (int j = 0; j < 15; ++j) xc[j] = xn[j];
    }
    #pragma unroll
    for (int w = 0; w < NV; ++w) h3s[w * NC + tid] = acc[w];
    __syncthreads();
    {
        const int wv = tid >> 6, lane = tid & 63;
        for (int w = wv; w < NV; w += 4) {
            float4 xq = *(const float4*)&h3s[w * NC + lane * 4];
            float s = xq.x + xq.y + xq.z + xq.w;
            float q = xq.x * xq.x + xq.y * xq.y + xq.z * xq.z + xq.w * xq.w;
            #pragma unroll
            for (int o = 32; o; o >>= 1) { s += __shfl_xor(s, o); q += __shfl_xor(q, o); }
            float mean = s * (1.f / 256.f);
            float var = fmaxf((q - 256.f * mean * mean) * (1.f / 255.f), 0.f);
            float inv = 1.f / (sqrtf(var) + LN_EPS);
            float o0 = bf2f(g3[lane * 4 + 0]) * (xq.x - mean) * inv + bf2f(b3[lane * 4 + 0]);
            float o1 = bf2f(g3[lane * 4 + 1]) * (xq.y - mean) * inv + bf2f(b3[lane * 4 + 1]);
            float o2 = bf2f(g3[lane * 4 + 2]) * (xq.z - mean) * inv + bf2f(b3[lane * 4 + 2]);
            float o3 = bf2f(g3[lane * 4 + 3]) * (xq.w - mean) * inv + bf2f(b3[lane * 4 + 3]);
            float* op = outp + (((size_t)(b * NT + t)) * NV + w) * NC + lane * 4;
            *(float4*)op = make_float4(o0, o1, o2, o3);
        }
    }
}

extern "C" void kernel_launch(void* const* d_in, const int* in_sizes, int n_in,
                              void* d_out, int out_size, void* d_ws, size_t ws_size,
                              hipStream_t stream)
{
    const size_t NTOK = (size_t)NB * NT * NV;   // 51200
    char* ws = (char*)d_ws;
    int* flag = (int*)ws;
    float* At3 = (float*)(ws + 256);            // [25][5][16] f32, 8KB
    float* cs4 = (float*)(ws + 256 + 8000);     // [25][4] f32, 400B
    ush* bufA = (ush*)(ws + 16384);             // [M,768]  78.6MB
    ush* bufB = bufA + NTOK * NKC;              // [M,256]  26.2MB
    ush* conv = bufB + NTOK * NC;

    k_detect<<<1, 256, 0, stream>>>((const uint32*)d_in[0], flag);
    k_convA<<<1, 256, 0, stream>>>(d_in[2], At3, cs4, flag);

    // ---- one-launch conversion table ----
    CvTab tab;
    int nent = 0, blk = 0;
    ush* p = conv;
    const ush* cp[18] = {};
    auto add = [&](int idx, int n, int K, int N, ush*& dst_out) {
        tab.e[nent] = { d_in[idx], p, n, K, N, blk };
        dst_out = p;
        blk += (K == 0) ? (n + 2047) / 2048 : (n + 1023) / 1024;
        p += (size_t)((n + 7) & ~7);
        ++nent;
    };
    ush* d;
    add(0, NB * NT * NV * NCIN, 0, 0, d);  cp[0] = d;
    add(1, NB * NTM * NV * NCM, 0, 0, d);  cp[1] = d;
    add(15, NKC, 0, 0, d);                 cp[15] = d;
    add(7, NC, 0, 0, d);  cp[7] = d;
    add(8, NC, 0, 0, d);  cp[8] = d;
    add(12, NC, 0, 0, d); cp[12] = d;
    add(13, NC, 0, 0, d); cp[13] = d;
    add(16, NC, 0, 0, d); cp[16] = d;
    add(17, NC, 0, 0, d); cp[17] = d;
    ush* w1t;
    add(4, NCIN * NC, NCIN, NC, w1t);      // [256][64] q
    add(5, NCIN * NC, NCIN, NC, d);        // k  (contiguous after q)
    add(6, NCIN * NC, NCIN, NC, d);        // v
    ush* wq2t;
    add(9, NC * NC, NC, NC, wq2t);         // [256][256]
    ush* wkv2t;
    add(10, NCM * NC, NCM, NC, wkv2t);     // [256][256] k
    add(11, NCM * NC, NCM, NC, d);         // v (contiguous)
    ush* wgt;
    add(14, NC * NKC, NC, NKC, wgt);       // [768][256]
    k_convall<<<blk, 256, 0, stream>>>(tab, flag);

    const int M = (int)NTOK;
    // stage 1: qkv1 = x @ [Wq1|Wk1|Wv1]  -> bufA [M,768]
    k_gemm<<<dim3(6, M / 128), 256, 0, stream>>>(cp[0], w1t, bufA, M, NCIN, NKC);
    k_attn_mfma<1><<<dim3(NV, NH, NB), 64, 0, stream>>>(bufA, bufB);
    k_ln<<<M / 4, 256, 0, stream>>>(bufB, cp[7], cp[8]);
    // stage 2: q2 = h1 @ Wq2 (cols 0-255); kv2 = m @ [Wk2|Wv2] (cols 256-767)
    k_gemm<<<dim3(2, M / 128), 256, 0, stream>>>(bufB, wq2t, bufA, M, NC, NKC);
    k_gemm<<<dim3(4, M / 128), 256, 0, stream>>>(cp[1], wkv2t, bufA + 256, M, NCM, NKC);
    k_attn_mfma<0><<<dim3(NV, NH, NB), 64, 0, stream>>>(bufA, bufB);
    k_ln<<<M / 4, 256, 0, stream>>>(bufB, cp[12], cp[13]);
    // stage 3: xw = h2 @ Wg -> bufA [M,768]; then GCN+LN -> out
    k_gemm<<<dim3(6, M / 128), 256, 0, stream>>>(bufB, wgt, bufA, M, NC, NKC);
    k_gcn<<<dim3(NT, NB), 256, 0, stream>>>(bufA, At3, cs4, cp[15], cp[16], cp[17],
                                            (float*)d_out);
}

// Round 12
// 281.702 us; speedup vs baseline: 1.3323x; 1.0680x over previous
//
#include <hip/hip_runtime.h>
#include <hip/hip_bf16.h>

typedef unsigned short ush;
typedef unsigned int uint32;
typedef __attribute__((ext_vector_type(8))) short s8v;   // 8 bf16 (4 VGPRs)
typedef __attribute__((ext_vector_type(4))) float f4v;   // MFMA accumulator

#define NB 16
#define NT 128
#define NTM 128
#define NV 25
#define NCIN 64
#define NCM 256
#define NH 8
#define ND 32
#define NC 256
#define NK 3
#define NKC 768
#define LN_EPS 1e-6f
#define QSCALE 0.17677669529663687f

__device__ __forceinline__ float bf2f(ush u) {
    union { uint32 i; float f; } x; x.i = ((uint32)u) << 16; return x.f;
}
__device__ __forceinline__ ush f2bf(float f) {
    union { float f; uint32 i; } x; x.f = f;
    uint32 r = x.i + 0x7FFFu + ((x.i >> 16) & 1u);
    return (ush)(r >> 16);
}
__device__ __forceinline__ uint32 pack2(float a, float b) {
    return (uint32)f2bf(a) | ((uint32)f2bf(b) << 16);
}

// -------- dtype detector (f32 vs bf16 device buffers) --------
__global__ __launch_bounds__(256) void k_detect(const uint32* __restrict__ xw,
                                               int* __restrict__ flag)
{
    __shared__ int cnt;
    if (threadIdx.x == 0) cnt = 0;
    __syncthreads();
    int c = 0;
    for (int i = 0; i < 4; ++i) {
        uint32 u = xw[threadIdx.x + 256 * i];
        uint32 e = (u >> 7) & 0xFF;
        c += (e >= 100 && e <= 135) ? 1 : 0;
    }
    atomicAdd(&cnt, c);
    __syncthreads();
    if (threadIdx.x == 0) *flag = (cnt > 700) ? 1 : 0;   // 1 = bf16, 0 = f32
}

// A [k][v][w] -> A2 bf16 [32 w][96 kk], kk = k*32+v (pad w>=25, v>=25 with 0)
//             + cs4[w][4]: cs4[w*4+k] = sum_v A[k][v][w]
__global__ __launch_bounds__(256) void k_convA(const void* __restrict__ src,
                                               ush* __restrict__ A2,
                                               float* __restrict__ cs4,
                                               const int* __restrict__ flag)
{
    const bool isbf = (*flag != 0);
    const int tid = threadIdx.x;
    __shared__ float As[1875];
    for (int i = tid; i < 1875; i += 256)
        As[i] = isbf ? bf2f(((const ush*)src)[i]) : ((const float*)src)[i];
    __syncthreads();
    for (int j = tid; j < 32 * 96; j += 256) {
        int w = j / 96, kk = j - w * 96, k = kk >> 5, v = kk & 31;
        float val = (w < NV && v < NV) ? As[k * 625 + v * 25 + w] : 0.f;
        A2[j] = f2bf(val);
    }
    for (int j = tid; j < 100; j += 256) {
        int w = j >> 2, k = j & 3;
        float s = 0.f;
        if (k < 3)
            for (int v = 0; v < NV; ++v) s += As[k * 625 + v * 25 + w];
        cs4[j] = s;
    }
}

// -------- single-launch converter --------
struct CvEnt { const void* src; ush* dst; int n; int K; int N; int blk0; };
struct CvTab { CvEnt e[16]; };

__global__ __launch_bounds__(256) void k_convall(CvTab tab, const int* __restrict__ flag)
{
    const bool isbf = (*flag != 0);
    const int bi = (int)blockIdx.x;
    int ei = 0;
    #pragma unroll
    for (int i = 1; i < 16; ++i) if (bi >= tab.e[i].blk0) ei = i;
    const CvEnt& e = tab.e[ei];
    if (e.K == 0) {
        const int idx = (bi - e.blk0) * 2048 + (int)threadIdx.x * 8;
        if (idx >= e.n) return;
        if (isbf) {
            *(uint4*)&e.dst[idx] = *(const uint4*)((const ush*)e.src + idx);
        } else {
            const float* s = (const float*)e.src + idx;
            uint4 a = *(const uint4*)s;
            uint4 b = *(const uint4*)(s + 4);
            uint4 o;
            o.x = pack2(((float*)&a)[0], ((float*)&a)[1]);
            o.y = pack2(((float*)&a)[2], ((float*)&a)[3]);
            o.z = pack2(((float*)&b)[0], ((float*)&b)[1]);
            o.w = pack2(((float*)&b)[2], ((float*)&b)[3]);
            *(uint4*)&e.dst[idx] = o;
        }
    } else {
        const int s4 = (bi - e.blk0) * 1024 + (int)threadIdx.x * 4;
        if (s4 >= e.n) return;
        const int k = s4 / e.N, n0 = s4 - k * e.N;
        float v0, v1, v2, v3;
        if (isbf) {
            const ush* s = (const ush*)e.src + s4;
            v0 = bf2f(s[0]); v1 = bf2f(s[1]); v2 = bf2f(s[2]); v3 = bf2f(s[3]);
        } else {
            float4 f = *(const float4*)((const float*)e.src + s4);
            v0 = f.x; v1 = f.y; v2 = f.z; v3 = f.w;
        }
        ush* d = e.dst + (size_t)n0 * e.K + k;
        d[0] = f2bf(v0);
        d[e.K] = f2bf(v1);
        d[2 * e.K] = f2bf(v2);
        d[3 * e.K] = f2bf(v3);
    }
}

// -------- MFMA GEMM: C[M, cols n0..] = A[M,K] @ Bt[N,K]^T --------
__global__ __launch_bounds__(256) void k_gemm(
    const ush* __restrict__ A, const ush* __restrict__ Bt, ush* __restrict__ C,
    int M, int K, int ldC)
{
    const int n0 = blockIdx.x * 128, m0 = blockIdx.y * 128;
    const int tid = threadIdx.x, w = tid >> 6, l = tid & 63;
    __shared__ ush As[8192], Bs[8192];
    const char* AsB = (const char*)As;
    const char* BsB = (const char*)Bs;
    const int rl = l >> 3, cc = l & 7;
    f4v acc[4][4] = {};
    const int wm = w >> 1, wn = w & 1;

    for (int kt = 0; kt < K; kt += 64) {
        __syncthreads();
        #pragma unroll
        for (int j = 0; j < 4; ++j) {
            const int r = (w * 4 + j) * 8 + rl;
            const int sc = (cc ^ (r & 7)) * 8;
            const ush* ga = &A[(size_t)(m0 + r) * K + kt + sc];
            const ush* gb = &Bt[(size_t)(n0 + r) * K + kt + sc];
            __builtin_amdgcn_global_load_lds(
                (const __attribute__((address_space(1))) uint32*)ga,
                (__attribute__((address_space(3))) uint32*)&As[(w * 4 + j) * 512], 16, 0, 0);
            __builtin_amdgcn_global_load_lds(
                (const __attribute__((address_space(1))) uint32*)gb,
                (__attribute__((address_space(3))) uint32*)&Bs[(w * 4 + j) * 512], 16, 0, 0);
        }
        __syncthreads();
        #pragma unroll
        for (int ks = 0; ks < 2; ++ks) {
            const int ko = ks * 64 + (l >> 4) * 16;
            s8v a[4], b[4];
            #pragma unroll
            for (int mi = 0; mi < 4; ++mi) {
                const int ra = wm * 64 + mi * 16 + (l & 15);
                a[mi] = *(const s8v*)(AsB + ra * 128 + (ko ^ ((ra & 7) << 4)));
            }
            #pragma unroll
            for (int ni = 0; ni < 4; ++ni) {
                const int rb = wn * 64 + ni * 16 + (l & 15);
                b[ni] = *(const s8v*)(BsB + rb * 128 + (ko ^ ((rb & 7) << 4)));
            }
            #pragma unroll
            for (int mi = 0; mi < 4; ++mi)
                #pragma unroll
                for (int ni = 0; ni < 4; ++ni)
                    acc[mi][ni] = __builtin_amdgcn_mfma_f32_16x16x32_bf16(a[mi], b[ni],
                                                                          acc[mi][ni], 0, 0, 0);
        }
    }
    const int col = n0 + wn * 64 + (l & 15);
    #pragma unroll
    for (int mi = 0; mi < 4; ++mi) {
        const int row_base = m0 + wm * 64 + mi * 16 + (l >> 4) * 4;
        #pragma unroll
        for (int ni = 0; ni < 4; ++ni)
            #pragma unroll
            for (int r = 0; r < 4; ++r)
                C[(size_t)(row_base + r) * ldC + col + ni * 16] = f2bf(acc[mi][ni][r]);
    }
}

// -------- MFMA attention: 1 wave = 1 (b,h,v) head; zero LDS --------
template<int MASKED>
__global__ __launch_bounds__(64) void k_attn_mfma(
    const ush* __restrict__ QKV, ush* __restrict__ O)
{
    const int v = blockIdx.x, h = blockIdx.y, b = blockIdx.z;
    const int l = threadIdx.x, g = l >> 4, c = l & 15;
    const size_t tokStride = (size_t)NV * NKC;
    const ush* base = QKV + ((size_t)b * NT * NV + v) * NKC;

    s8v kf[8];
    const int koff = 256 + h * ND + g * 8;
    #pragma unroll
    for (int si = 0; si < 8; ++si)
        kf[si] = *(const s8v*)(base + (size_t)(16 * si + c) * tokStride + koff);

    s8v vf[4][2];
    #pragma unroll
    for (int ks = 0; ks < 4; ++ks)
        #pragma unroll
        for (int ni = 0; ni < 2; ++ni) {
            const int voff = 512 + h * ND + 16 * ni + c;
            s8v tmp;
            #pragma unroll
            for (int j = 0; j < 8; ++j)
                tmp[j] = (short)base[(size_t)(32 * ks + 8 * g + j) * tokStride + voff];
            vf[ks][ni] = tmp;
        }

    ush* og = O + ((size_t)b * NT * NV + v) * NC + h * ND;
    const int qoff = h * ND + g * 8;
    const int ga = (g & 1) * 2;
    const int l1 = ga * 16 + c, l2 = l1 + 16;
    const bool hisel = (g >> 1) != 0;

    for (int t16 = 0; t16 < 8; ++t16) {
        s8v qf = *(const s8v*)(base + (size_t)(16 * t16 + c) * tokStride + qoff);
        f4v st[8];
        #pragma unroll
        for (int si = 0; si < 8; ++si)
            st[si] = __builtin_amdgcn_mfma_f32_16x16x32_bf16(kf[si], qf,
                                                             (f4v){0.f, 0.f, 0.f, 0.f}, 0, 0, 0);
        const int t = 16 * t16 + c;
        if (MASKED) {
            #pragma unroll
            for (int si = 0; si < 8; ++si)
                #pragma unroll
                for (int r = 0; r < 4; ++r)
                    if (16 * si + 4 * g + r > t) st[si][r] = -1e30f;
        }
        float mx = -1e30f;
        #pragma unroll
        for (int si = 0; si < 8; ++si)
            #pragma unroll
            for (int r = 0; r < 4; ++r) mx = fmaxf(mx, st[si][r]);
        mx = fmaxf(mx, __shfl_xor(mx, 16));
        mx = fmaxf(mx, __shfl_xor(mx, 32));
        float sm = 0.f;
        #pragma unroll
        for (int si = 0; si < 8; ++si)
            #pragma unroll
            for (int r = 0; r < 4; ++r) {
                float e = __expf((st[si][r] - mx) * QSCALE);
                st[si][r] = e;
                sm += e;
            }
        sm += __shfl_xor(sm, 16);
        sm += __shfl_xor(sm, 32);
        const float inv = 1.f / sm;
        uint32 u[8][2];
        #pragma unroll
        for (int si = 0; si < 8; ++si) {
            float e0 = st[si][0] * inv, e1 = st[si][1] * inv;
            float e2 = st[si][2] * inv, e3 = st[si][3] * inv;
            asm("v_cvt_pk_bf16_f32 %0, %1, %2" : "=v"(u[si][0]) : "v"(e0), "v"(e1));
            asm("v_cvt_pk_bf16_f32 %0, %1, %2" : "=v"(u[si][1]) : "v"(e2), "v"(e3));
        }
        f4v o[2] = {};
        #pragma unroll
        for (int ks = 0; ks < 4; ++ks) {
            uint32 w0a = __shfl(u[2 * ks][0], l1),     w0b = __shfl(u[2 * ks][1], l1);
            uint32 w0c = __shfl(u[2 * ks][0], l2),     w0d = __shfl(u[2 * ks][1], l2);
            uint32 w1a = __shfl(u[2 * ks + 1][0], l1), w1b = __shfl(u[2 * ks + 1][1], l1);
            uint32 w1c = __shfl(u[2 * ks + 1][0], l2), w1d = __shfl(u[2 * ks + 1][1], l2);
            union { uint32 w[4]; s8v s; } pa;
            pa.w[0] = hisel ? w1a : w0a;
            pa.w[1] = hisel ? w1b : w0b;
            pa.w[2] = hisel ? w1c : w0c;
            pa.w[3] = hisel ? w1d : w0d;
            o[0] = __builtin_amdgcn_mfma_f32_16x16x32_bf16(pa.s, vf[ks][0], o[0], 0, 0, 0);
            o[1] = __builtin_amdgcn_mfma_f32_16x16x32_bf16(pa.s, vf[ks][1], o[1], 0, 0, 0);
        }
        #pragma unroll
        for (int ni = 0; ni < 2; ++ni)
            #pragma unroll
            for (int r = 0; r < 4; ++r)
                og[(size_t)(16 * t16 + 4 * g + r) * (NV * NC) + 16 * ni + c] = f2bf(o[ni][r]);
    }
}

// ---------------- row LayerNorm (unbiased std), in place, 1 wave = 1 row ----------------
__global__ __launch_bounds__(256) void k_ln(
    ush* __restrict__ buf, const ush* __restrict__ g, const ush* __restrict__ bb)
{
    const int row = blockIdx.x * 4 + (threadIdx.x >> 6);
    const int lane = threadIdx.x & 63;
    ush* p = buf + (size_t)row * NC + lane * 4;
    uint2 u = *(uint2*)p;
    float x0 = bf2f((ush)(u.x & 0xffff)), x1 = bf2f((ush)(u.x >> 16));
    float x2 = bf2f((ush)(u.y & 0xffff)), x3 = bf2f((ush)(u.y >> 16));
    float s = x0 + x1 + x2 + x3;
    float q = x0 * x0 + x1 * x1 + x2 * x2 + x3 * x3;
    #pragma unroll
    for (int o = 32; o; o >>= 1) { s += __shfl_xor(s, o); q += __shfl_xor(q, o); }
    float mean = s * (1.f / 256.f);
    float var = fmaxf((q - 256.f * mean * mean) * (1.f / 255.f), 0.f);
    float inv = 1.f / (sqrtf(var) + LN_EPS);
    float o0 = bf2f(g[lane * 4 + 0]) * (x0 - mean) * inv + bf2f(bb[lane * 4 + 0]);
    float o1 = bf2f(g[lane * 4 + 1]) * (x1 - mean) * inv + bf2f(bb[lane * 4 + 1]);
    float o2 = bf2f(g[lane * 4 + 2]) * (x2 - mean) * inv + bf2f(bb[lane * 4 + 2]);
    float o3 = bf2f(g[lane * 4 + 3]) * (x3 - mean) * inv + bf2f(bb[lane * 4 + 3]);
    uint32 lo = (uint32)f2bf(o0) | ((uint32)f2bf(o1) << 16);
    uint32 hi = (uint32)f2bf(o2) | ((uint32)f2bf(o3) << 16);
    *(uint2*)p = make_uint2(lo, hi);
}

// -------- GCN via MFMA: per (b,t): h3[32 w][256 c] = A2[32][96] @ X[96][256] --------
// X[kk = k*32+v][c] = xw[bt, v, k*256+c]; LDS-staged with XOR swizzle;
// b-frags gathered as 8x ds_read_u16; bias + LN fused epilogue.
__global__ __launch_bounds__(256) void k_gcn_mfma(
    const ush* __restrict__ xw, const ush* __restrict__ A2,
    const float* __restrict__ cs4,
    const ush* __restrict__ bg, const ush* __restrict__ g3, const ush* __restrict__ b3,
    float* __restrict__ outp)
{
    const int t = blockIdx.x, b = blockIdx.y;
    const int tid = threadIdx.x;
    __shared__ uint4 Xs4[2400];                 // 38.4KB: X tile, swizzled
    char* Xs = (char*)Xs4;
    float* h3s = (float*)Xs4;                   // [25][260] f32 overlay after barrier
    const int l = tid & 63, wv = tid >> 6, g = l >> 4, c4 = l & 15;

    // a-frags (global, L2-hot; before barrier)
    s8v af[2][3];
    #pragma unroll
    for (int mi = 0; mi < 2; ++mi)
        #pragma unroll
        for (int ks = 0; ks < 3; ++ks)
            af[mi][ks] = *(const s8v*)&A2[(mi * 16 + c4) * 96 + ks * 32 + g * 8];

    // stage X: coalesced uint4 reads, swizzled LDS writes
    const ush* xr = xw + ((size_t)(b * NT + t)) * NV * NKC;
    for (int i = tid; i < 2400; i += 256) {
        int v = i / 96, c8 = i - v * 96;
        uint32 off = (uint32)(v * 1536 + c8 * 16) ^ (((v >> 3) & 3) << 4);
        *(uint4*)(Xs + off) = *(const uint4*)&xr[(size_t)v * NKC + c8 * 8];
    }
    __syncthreads();

    f4v acc[2][4] = {};
    const int c0 = wv * 64;
    #pragma unroll
    for (int ks = 0; ks < 3; ++ks) {
        #pragma unroll
        for (int ni = 0; ni < 4; ++ni) {
            const int c = c0 + ni * 16 + c4;
            s8v bfr;
            #pragma unroll
            for (int j = 0; j < 8; ++j) {
                int v = g * 8 + j; if (v > 24) v = 24;   // pad lanes: A2=0, avoid OOB
                uint32 off = (uint32)(v * 1536 + ks * 512 + c * 2) ^ (((v >> 3) & 3) << 4);
                bfr[j] = *(const short*)(Xs + off);
            }
            acc[0][ni] = __builtin_amdgcn_mfma_f32_16x16x32_bf16(af[0][ks], bfr, acc[0][ni], 0, 0, 0);
            acc[1][ni] = __builtin_amdgcn_mfma_f32_16x16x32_bf16(af[1][ks], bfr, acc[1][ni], 0, 0, 0);
        }
    }
    __syncthreads();   // all waves done reading Xs -> overlay h3s
    #pragma unroll
    for (int mi = 0; mi < 2; ++mi)
        #pragma unroll
        for (int r = 0; r < 4; ++r) {
            const int w = mi * 16 + g * 4 + r;
            if (w < NV) {
                #pragma unroll
                for (int ni = 0; ni < 4; ++ni)
                    h3s[w * 260 + c0 + ni * 16 + c4] = acc[mi][ni][r];
            }
        }
    __syncthreads();
    {   // bias + LN + f32 out
        const int lane = tid & 63;
        float bgq[3][4];
        #pragma unroll
        for (int k = 0; k < 3; ++k)
            #pragma unroll
            for (int i = 0; i < 4; ++i)
                bgq[k][i] = bf2f(bg[k * NC + lane * 4 + i]);
        for (int w = wv; w < NV; w += 4) {
            float4 xq = *(const float4*)&h3s[w * 260 + lane * 4];
            const float cw0 = cs4[w * 4], cw1 = cs4[w * 4 + 1], cw2 = cs4[w * 4 + 2];
            xq.x += cw0 * bgq[0][0] + cw1 * bgq[1][0] + cw2 * bgq[2][0];
            xq.y += cw0 * bgq[0][1] + cw1 * bgq[1][1] + cw2 * bgq[2][1];
            xq.z += cw0 * bgq[0][2] + cw1 * bgq[1][2] + cw2 * bgq[2][2];
            xq.w += cw0 * bgq[0][3] + cw1 * bgq[1][3] + cw2 * bgq[2][3];
            float s = xq.x + xq.y + xq.z + xq.w;
            float q = xq.x * xq.x + xq.y * xq.y + xq.z * xq.z + xq.w * xq.w;
            #pragma unroll
            for (int o = 32; o; o >>= 1) { s += __shfl_xor(s, o); q += __shfl_xor(q, o); }
            float mean = s * (1.f / 256.f);
            float var = fmaxf((q - 256.f * mean * mean) * (1.f / 255.f), 0.f);
            float inv = 1.f / (sqrtf(var) + LN_EPS);
            float o0 = bf2f(g3[lane * 4 + 0]) * (xq.x - mean) * inv + bf2f(b3[lane * 4 + 0]);
            float o1 = bf2f(g3[lane * 4 + 1]) * (xq.y - mean) * inv + bf2f(b3[lane * 4 + 1]);
            float o2 = bf2f(g3[lane * 4 + 2]) * (xq.z - mean) * inv + bf2f(b3[lane * 4 + 2]);
            float o3 = bf2f(g3[lane * 4 + 3]) * (xq.w - mean) * inv + bf2f(b3[lane * 4 + 3]);
            float* op = outp + (((size_t)(b * NT + t)) * NV + w) * NC + lane * 4;
            *(float4*)op = make_float4(o0, o1, o2, o3);
        }
    }
}

extern "C" void kernel_launch(void* const* d_in, const int* in_sizes, int n_in,
                              void* d_out, int out_size, void* d_ws, size_t ws_size,
                              hipStream_t stream)
{
    const size_t NTOK = (size_t)NB * NT * NV;   // 51200
    char* ws = (char*)d_ws;
    int* flag = (int*)ws;
    ush* A2 = (ush*)(ws + 256);                 // [32][96] bf16, 6KB
    float* cs4 = (float*)(ws + 256 + 6144);     // [25][4] f32, 400B
    ush* bufA = (ush*)(ws + 16384);             // [M,768]  78.6MB
    ush* bufB = bufA + NTOK * NKC;              // [M,256]  26.2MB
    ush* conv = bufB + NTOK * NC;

    k_detect<<<1, 256, 0, stream>>>((const uint32*)d_in[0], flag);
    k_convA<<<1, 256, 0, stream>>>(d_in[2], A2, cs4, flag);

    // ---- one-launch conversion table ----
    CvTab tab;
    int nent = 0, blk = 0;
    ush* p = conv;
    const ush* cp[18] = {};
    auto add = [&](int idx, int n, int K, int N, ush*& dst_out) {
        tab.e[nent] = { d_in[idx], p, n, K, N, blk };
        dst_out = p;
        blk += (K == 0) ? (n + 2047) / 2048 : (n + 1023) / 1024;
        p += (size_t)((n + 7) & ~7);
        ++nent;
    };
    ush* d;
    add(0, NB * NT * NV * NCIN, 0, 0, d);  cp[0] = d;
    add(1, NB * NTM * NV * NCM, 0, 0, d);  cp[1] = d;
    add(15, NKC, 0, 0, d);                 cp[15] = d;
    add(7, NC, 0, 0, d);  cp[7] = d;
    add(8, NC, 0, 0, d);  cp[8] = d;
    add(12, NC, 0, 0, d); cp[12] = d;
    add(13, NC, 0, 0, d); cp[13] = d;
    add(16, NC, 0, 0, d); cp[16] = d;
    add(17, NC, 0, 0, d); cp[17] = d;
    ush* w1t;
    add(4, NCIN * NC, NCIN, NC, w1t);      // [256][64] q
    add(5, NCIN * NC, NCIN, NC, d);        // k  (contiguous after q)
    add(6, NCIN * NC, NCIN, NC, d);        // v
    ush* wq2t;
    add(9, NC * NC, NC, NC, wq2t);         // [256][256]
    ush* wkv2t;
    add(10, NCM * NC, NCM, NC, wkv2t);     // [256][256] k
    add(11, NCM * NC, NCM, NC, d);         // v (contiguous)
    ush* wgt;
    add(14, NC * NKC, NC, NKC, wgt);       // [768][256]
    k_convall<<<blk, 256, 0, stream>>>(tab, flag);

    const int M = (int)NTOK;
    // stage 1: qkv1 = x @ [Wq1|Wk1|Wv1]  -> bufA [M,768]
    k_gemm<<<dim3(6, M / 128), 256, 0, stream>>>(cp[0], w1t, bufA, M, NCIN, NKC);
    k_attn_mfma<1><<<dim3(NV, NH, NB), 64, 0, stream>>>(bufA, bufB);
    k_ln<<<M / 4, 256, 0, stream>>>(bufB, cp[7], cp[8]);
    // stage 2: q2 = h1 @ Wq2 (cols 0-255); kv2 = m @ [Wk2|Wv2] (cols 256-767)
    k_gemm<<<dim3(2, M / 128), 256, 0, stream>>>(bufB, wq2t, bufA, M, NC, NKC);
    k_gemm<<<dim3(4, M / 128), 256, 0, stream>>>(cp[1], wkv2t, bufA + 256, M, NCM, NKC);
    k_attn_mfma<0><<<dim3(NV, NH, NB), 64, 0, stream>>>(bufA, bufB);
    k_ln<<<M / 4, 256, 0, stream>>>(bufB, cp[12], cp[13]);
    // stage 3: xw = h2 @ Wg -> bufA [M,768]; then MFMA GCN + LN -> out
    k_gemm<<<dim3(6, M / 128), 256, 0, stream>>>(bufB, wgt, bufA, M, NC, NKC);
    k_gcn_mfma<<<dim3(NT, NB), 256, 0, stream>>>(bufA, A2, cs4, cp[15], cp[16], cp[17],
                                                 (float*)d_out);
}

// Round 13
// 270.111 us; speedup vs baseline: 1.3895x; 1.0429x over previous
//
#include <hip/hip_runtime.h>
#include <hip/hip_bf16.h>

typedef unsigned short ush;
typedef unsigned int uint32;
typedef __attribute__((ext_vector_type(8))) short s8v;   // 8 bf16 (4 VGPRs)
typedef __attribute__((ext_vector_type(4))) float f4v;   // MFMA accumulator

#define NB 16
#define NT 128
#define NTM 128
#define NV 25
#define NCIN 64
#define NCM 256
#define NH 8
#define ND 32
#define NC 256
#define NK 3
#define NKC 768
#define LN_EPS 1e-6f
#define QSCALE 0.17677669529663687f

__device__ __forceinline__ float bf2f(ush u) {
    union { uint32 i; float f; } x; x.i = ((uint32)u) << 16; return x.f;
}
__device__ __forceinline__ ush f2bf(float f) {
    union { float f; uint32 i; } x; x.f = f;
    uint32 r = x.i + 0x7FFFu + ((x.i >> 16) & 1u);
    return (ush)(r >> 16);
}
__device__ __forceinline__ uint32 pack2(float a, float b) {
    return (uint32)f2bf(a) | ((uint32)f2bf(b) << 16);
}

// -------- dtype detector (f32 vs bf16 device buffers) --------
__global__ __launch_bounds__(256) void k_detect(const uint32* __restrict__ xw,
                                               int* __restrict__ flag)
{
    __shared__ int cnt;
    if (threadIdx.x == 0) cnt = 0;
    __syncthreads();
    int c = 0;
    for (int i = 0; i < 4; ++i) {
        uint32 u = xw[threadIdx.x + 256 * i];
        uint32 e = (u >> 7) & 0xFF;
        c += (e >= 100 && e <= 135) ? 1 : 0;
    }
    atomicAdd(&cnt, c);
    __syncthreads();
    if (threadIdx.x == 0) *flag = (cnt > 700) ? 1 : 0;   // 1 = bf16, 0 = f32
}

// A [k][v][w] -> A2 bf16 [32 w][96 kk], kk = k*32+v (pad w>=25, v>=25 with 0)
//             + cs4[w][4]: cs4[w*4+k] = sum_v A[k][v][w]
__global__ __launch_bounds__(256) void k_convA(const void* __restrict__ src,
                                               ush* __restrict__ A2,
                                               float* __restrict__ cs4,
                                               const int* __restrict__ flag)
{
    const bool isbf = (*flag != 0);
    const int tid = threadIdx.x;
    __shared__ float As[1875];
    for (int i = tid; i < 1875; i += 256)
        As[i] = isbf ? bf2f(((const ush*)src)[i]) : ((const float*)src)[i];
    __syncthreads();
    for (int j = tid; j < 32 * 96; j += 256) {
        int w = j / 96, kk = j - w * 96, k = kk >> 5, v = kk & 31;
        float val = (w < NV && v < NV) ? As[k * 625 + v * 25 + w] : 0.f;
        A2[j] = f2bf(val);
    }
    for (int j = tid; j < 100; j += 256) {
        int w = j >> 2, k = j & 3;
        float s = 0.f;
        if (k < 3)
            for (int v = 0; v < NV; ++v) s += As[k * 625 + v * 25 + w];
        cs4[j] = s;
    }
}

// -------- single-launch converter --------
struct CvEnt { const void* src; ush* dst; int n; int K; int N; int blk0; };
struct CvTab { CvEnt e[16]; };

__global__ __launch_bounds__(256) void k_convall(CvTab tab, const int* __restrict__ flag)
{
    const bool isbf = (*flag != 0);
    const int bi = (int)blockIdx.x;
    int ei = 0;
    #pragma unroll
    for (int i = 1; i < 16; ++i) if (bi >= tab.e[i].blk0) ei = i;
    const CvEnt& e = tab.e[ei];
    if (e.K == 0) {
        const int idx = (bi - e.blk0) * 2048 + (int)threadIdx.x * 8;
        if (idx >= e.n) return;
        if (isbf) {
            *(uint4*)&e.dst[idx] = *(const uint4*)((const ush*)e.src + idx);
        } else {
            const float* s = (const float*)e.src + idx;
            uint4 a = *(const uint4*)s;
            uint4 b = *(const uint4*)(s + 4);
            uint4 o;
            o.x = pack2(((float*)&a)[0], ((float*)&a)[1]);
            o.y = pack2(((float*)&a)[2], ((float*)&a)[3]);
            o.z = pack2(((float*)&b)[0], ((float*)&b)[1]);
            o.w = pack2(((float*)&b)[2], ((float*)&b)[3]);
            *(uint4*)&e.dst[idx] = o;
        }
    } else {
        const int s4 = (bi - e.blk0) * 1024 + (int)threadIdx.x * 4;
        if (s4 >= e.n) return;
        const int k = s4 / e.N, n0 = s4 - k * e.N;
        float v0, v1, v2, v3;
        if (isbf) {
            const ush* s = (const ush*)e.src + s4;
            v0 = bf2f(s[0]); v1 = bf2f(s[1]); v2 = bf2f(s[2]); v3 = bf2f(s[3]);
        } else {
            float4 f = *(const float4*)((const float*)e.src + s4);
            v0 = f.x; v1 = f.y; v2 = f.z; v3 = f.w;
        }
        ush* d = e.dst + (size_t)n0 * e.K + k;
        d[0] = f2bf(v0);
        d[e.K] = f2bf(v1);
        d[2 * e.K] = f2bf(v2);
        d[3 * e.K] = f2bf(v3);
    }
}

// -------- MFMA GEMM: C[M, cols n0..] = A[M,K] @ Bt[N,K]^T --------
__global__ __launch_bounds__(256) void k_gemm(
    const ush* __restrict__ A, const ush* __restrict__ Bt, ush* __restrict__ C,
    int M, int K, int ldC)
{
    const int n0 = blockIdx.x * 128, m0 = blockIdx.y * 128;
    const int tid = threadIdx.x, w = tid >> 6, l = tid & 63;
    __shared__ ush As[8192], Bs[8192];
    const char* AsB = (const char*)As;
    const char* BsB = (const char*)Bs;
    const int rl = l >> 3, cc = l & 7;
    f4v acc[4][4] = {};
    const int wm = w >> 1, wn = w & 1;

    for (int kt = 0; kt < K; kt += 64) {
        __syncthreads();
        #pragma unroll
        for (int j = 0; j < 4; ++j) {
            const int r = (w * 4 + j) * 8 + rl;
            const int sc = (cc ^ (r & 7)) * 8;
            const ush* ga = &A[(size_t)(m0 + r) * K + kt + sc];
            const ush* gb = &Bt[(size_t)(n0 + r) * K + kt + sc];
            __builtin_amdgcn_global_load_lds(
                (const __attribute__((address_space(1))) uint32*)ga,
                (__attribute__((address_space(3))) uint32*)&As[(w * 4 + j) * 512], 16, 0, 0);
            __builtin_amdgcn_global_load_lds(
                (const __attribute__((address_space(1))) uint32*)gb,
                (__attribute__((address_space(3))) uint32*)&Bs[(w * 4 + j) * 512], 16, 0, 0);
        }
        __syncthreads();
        #pragma unroll
        for (int ks = 0; ks < 2; ++ks) {
            const int ko = ks * 64 + (l >> 4) * 16;
            s8v a[4], b[4];
            #pragma unroll
            for (int mi = 0; mi < 4; ++mi) {
                const int ra = wm * 64 + mi * 16 + (l & 15);
                a[mi] = *(const s8v*)(AsB + ra * 128 + (ko ^ ((ra & 7) << 4)));
            }
            #pragma unroll
            for (int ni = 0; ni < 4; ++ni) {
                const int rb = wn * 64 + ni * 16 + (l & 15);
                b[ni] = *(const s8v*)(BsB + rb * 128 + (ko ^ ((rb & 7) << 4)));
            }
            #pragma unroll
            for (int mi = 0; mi < 4; ++mi)
                #pragma unroll
                for (int ni = 0; ni < 4; ++ni)
                    acc[mi][ni] = __builtin_amdgcn_mfma_f32_16x16x32_bf16(a[mi], b[ni],
                                                                          acc[mi][ni], 0, 0, 0);
        }
    }
    const int col = n0 + wn * 64 + (l & 15);
    #pragma unroll
    for (int mi = 0; mi < 4; ++mi) {
        const int row_base = m0 + wm * 64 + mi * 16 + (l >> 4) * 4;
        #pragma unroll
        for (int ni = 0; ni < 4; ++ni)
            #pragma unroll
            for (int r = 0; r < 4; ++r)
                C[(size_t)(row_base + r) * ldC + col + ni * 16] = f2bf(acc[mi][ni][r]);
    }
}

// -------- MFMA attention: 4 heads per 256-thread block; V staged in LDS --------
template<int MASKED>
__global__ __launch_bounds__(256) void k_attn_mfma(
    const ush* __restrict__ QKV, ush* __restrict__ O)
{
    const int v = blockIdx.x, hq = blockIdx.y, b = blockIdx.z;
    const int tid = threadIdx.x, wv = tid >> 6, l = tid & 63;
    const int h = hq * 4 + wv;
    const int g = l >> 4, c = l & 15;
    __shared__ ush Vs[4][NT * ND];   // 32 KB: per-wave V tile, linear [128][32]
    const size_t tokStride = (size_t)NV * NKC;
    const ush* base = QKV + ((size_t)b * NT * NV + v) * NKC;

    // stage V: 8 coalesced s8v loads -> LDS
    const int vrow = l >> 2, vch = (l & 3) * 8;
    #pragma unroll
    for (int i = 0; i < 8; ++i) {
        s8v rv = *(const s8v*)(base + (size_t)(16 * i + vrow) * tokStride + 512 + h * ND + vch);
        *(s8v*)&Vs[wv][(16 * i + vrow) * ND + vch] = rv;
    }
    // K fragments from global
    s8v kf[8];
    const int koff = 256 + h * ND + g * 8;
    #pragma unroll
    for (int si = 0; si < 8; ++si)
        kf[si] = *(const s8v*)(base + (size_t)(16 * si + c) * tokStride + koff);
    __syncthreads();
    // V^T fragments from LDS: vf[ks][ni][j] = V[32ks+8g+j][16ni+c]
    s8v vf[4][2];
    #pragma unroll
    for (int ks = 0; ks < 4; ++ks)
        #pragma unroll
        for (int ni = 0; ni < 2; ++ni) {
            s8v tmp;
            #pragma unroll
            for (int j = 0; j < 8; ++j)
                tmp[j] = (short)Vs[wv][(32 * ks + 8 * g + j) * ND + 16 * ni + c];
            vf[ks][ni] = tmp;
        }

    ush* og = O + ((size_t)b * NT * NV + v) * NC + h * ND;
    const int qoff = h * ND + g * 8;
    const int ga = (g & 1) * 2;
    const int l1 = ga * 16 + c, l2 = l1 + 16;
    const bool hisel = (g >> 1) != 0;

    for (int t16 = 0; t16 < 8; ++t16) {
        s8v qf = *(const s8v*)(base + (size_t)(16 * t16 + c) * tokStride + qoff);
        f4v st[8];
        #pragma unroll
        for (int si = 0; si < 8; ++si)
            st[si] = __builtin_amdgcn_mfma_f32_16x16x32_bf16(kf[si], qf,
                                                             (f4v){0.f, 0.f, 0.f, 0.f}, 0, 0, 0);
        const int t = 16 * t16 + c;
        if (MASKED) {
            #pragma unroll
            for (int si = 0; si < 8; ++si)
                #pragma unroll
                for (int r = 0; r < 4; ++r)
                    if (16 * si + 4 * g + r > t) st[si][r] = -1e30f;
        }
        float mx = -1e30f;
        #pragma unroll
        for (int si = 0; si < 8; ++si)
            #pragma unroll
            for (int r = 0; r < 4; ++r) mx = fmaxf(mx, st[si][r]);
        mx = fmaxf(mx, __shfl_xor(mx, 16));
        mx = fmaxf(mx, __shfl_xor(mx, 32));
        float sm = 0.f;
        #pragma unroll
        for (int si = 0; si < 8; ++si)
            #pragma unroll
            for (int r = 0; r < 4; ++r) {
                float e = __expf((st[si][r] - mx) * QSCALE);
                st[si][r] = e;
                sm += e;
            }
        sm += __shfl_xor(sm, 16);
        sm += __shfl_xor(sm, 32);
        const float inv = 1.f / sm;
        uint32 u[8][2];
        #pragma unroll
        for (int si = 0; si < 8; ++si) {
            float e0 = st[si][0] * inv, e1 = st[si][1] * inv;
            float e2 = st[si][2] * inv, e3 = st[si][3] * inv;
            asm("v_cvt_pk_bf16_f32 %0, %1, %2" : "=v"(u[si][0]) : "v"(e0), "v"(e1));
            asm("v_cvt_pk_bf16_f32 %0, %1, %2" : "=v"(u[si][1]) : "v"(e2), "v"(e3));
        }
        f4v o[2] = {};
        #pragma unroll
        for (int ks = 0; ks < 4; ++ks) {
            uint32 w0a = __shfl(u[2 * ks][0], l1),     w0b = __shfl(u[2 * ks][1], l1);
            uint32 w0c = __shfl(u[2 * ks][0], l2),     w0d = __shfl(u[2 * ks][1], l2);
            uint32 w1a = __shfl(u[2 * ks + 1][0], l1), w1b = __shfl(u[2 * ks + 1][1], l1);
            uint32 w1c = __shfl(u[2 * ks + 1][0], l2), w1d = __shfl(u[2 * ks + 1][1], l2);
            union { uint32 w[4]; s8v s; } pa;
            pa.w[0] = hisel ? w1a : w0a;
            pa.w[1] = hisel ? w1b : w0b;
            pa.w[2] = hisel ? w1c : w0c;
            pa.w[3] = hisel ? w1d : w0d;
            o[0] = __builtin_amdgcn_mfma_f32_16x16x32_bf16(pa.s, vf[ks][0], o[0], 0, 0, 0);
            o[1] = __builtin_amdgcn_mfma_f32_16x16x32_bf16(pa.s, vf[ks][1], o[1], 0, 0, 0);
        }
        #pragma unroll
        for (int ni = 0; ni < 2; ++ni)
            #pragma unroll
            for (int r = 0; r < 4; ++r)
                og[(size_t)(16 * t16 + 4 * g + r) * (NV * NC) + 16 * ni + c] = f2bf(o[ni][r]);
    }
}

// ---------------- row LayerNorm (unbiased std), in place, 1 wave = 1 row ----------------
__global__ __launch_bounds__(256) void k_ln(
    ush* __restrict__ buf, const ush* __restrict__ g, const ush* __restrict__ bb)
{
    const int row = blockIdx.x * 4 + (threadIdx.x >> 6);
    const int lane = threadIdx.x & 63;
    ush* p = buf + (size_t)row * NC + lane * 4;
    uint2 u = *(uint2*)p;
    float x0 = bf2f((ush)(u.x & 0xffff)), x1 = bf2f((ush)(u.x >> 16));
    float x2 = bf2f((ush)(u.y & 0xffff)), x3 = bf2f((ush)(u.y >> 16));
    float s = x0 + x1 + x2 + x3;
    float q = x0 * x0 + x1 * x1 + x2 * x2 + x3 * x3;
    #pragma unroll
    for (int o = 32; o; o >>= 1) { s += __shfl_xor(s, o); q += __shfl_xor(q, o); }
    float mean = s * (1.f / 256.f);
    float var = fmaxf((q - 256.f * mean * mean) * (1.f / 255.f), 0.f);
    float inv = 1.f / (sqrtf(var) + LN_EPS);
    float o0 = bf2f(g[lane * 4 + 0]) * (x0 - mean) * inv + bf2f(bb[lane * 4 + 0]);
    float o1 = bf2f(g[lane * 4 + 1]) * (x1 - mean) * inv + bf2f(bb[lane * 4 + 1]);
    float o2 = bf2f(g[lane * 4 + 2]) * (x2 - mean) * inv + bf2f(bb[lane * 4 + 2]);
    float o3 = bf2f(g[lane * 4 + 3]) * (x3 - mean) * inv + bf2f(bb[lane * 4 + 3]);
    uint32 lo = (uint32)f2bf(o0) | ((uint32)f2bf(o1) << 16);
    uint32 hi = (uint32)f2bf(o2) | ((uint32)f2bf(o3) << 16);
    *(uint2*)p = make_uint2(lo, hi);
}

// -------- GCN via MFMA: per (b,t): h3[32 w][256 c] = A2[32][96] @ X[96][256] --------
__global__ __launch_bounds__(256) void k_gcn_mfma(
    const ush* __restrict__ xw, const ush* __restrict__ A2,
    const float* __restrict__ cs4,
    const ush* __restrict__ bg, const ush* __restrict__ g3, const ush* __restrict__ b3,
    float* __restrict__ outp)
{
    const int t = blockIdx.x, b = blockIdx.y;
    const int tid = threadIdx.x;
    __shared__ uint4 Xs4[2400];                 // 38.4KB: X tile, swizzled
    char* Xs = (char*)Xs4;
    float* h3s = (float*)Xs4;                   // [25][260] f32 overlay after barrier
    const int l = tid & 63, wv = tid >> 6, g = l >> 4, c4 = l & 15;

    s8v af[2][3];
    #pragma unroll
    for (int mi = 0; mi < 2; ++mi)
        #pragma unroll
        for (int ks = 0; ks < 3; ++ks)
            af[mi][ks] = *(const s8v*)&A2[(mi * 16 + c4) * 96 + ks * 32 + g * 8];

    const ush* xr = xw + ((size_t)(b * NT + t)) * NV * NKC;
    for (int i = tid; i < 2400; i += 256) {
        int v = i / 96, c8 = i - v * 96;
        uint32 off = (uint32)(v * 1536 + c8 * 16) ^ (((v >> 3) & 3) << 4);
        *(uint4*)(Xs + off) = *(const uint4*)&xr[(size_t)v * NKC + c8 * 8];
    }
    __syncthreads();

    f4v acc[2][4] = {};
    const int c0 = wv * 64;
    #pragma unroll
    for (int ks = 0; ks < 3; ++ks) {
        #pragma unroll
        for (int ni = 0; ni < 4; ++ni) {
            const int c = c0 + ni * 16 + c4;
            s8v bfr;
            #pragma unroll
            for (int j = 0; j < 8; ++j) {
                int v = g * 8 + j; if (v > 24) v = 24;
                uint32 off = (uint32)(v * 1536 + ks * 512 + c * 2) ^ (((v >> 3) & 3) << 4);
                bfr[j] = *(const short*)(Xs + off);
            }
            acc[0][ni] = __builtin_amdgcn_mfma_f32_16x16x32_bf16(af[0][ks], bfr, acc[0][ni], 0, 0, 0);
            acc[1][ni] = __builtin_amdgcn_mfma_f32_16x16x32_bf16(af[1][ks], bfr, acc[1][ni], 0, 0, 0);
        }
    }
    __syncthreads();
    #pragma unroll
    for (int mi = 0; mi < 2; ++mi)
        #pragma unroll
        for (int r = 0; r < 4; ++r) {
            const int w = mi * 16 + g * 4 + r;
            if (w < NV) {
                #pragma unroll
                for (int ni = 0; ni < 4; ++ni)
                    h3s[w * 260 + c0 + ni * 16 + c4] = acc[mi][ni][r];
            }
        }
    __syncthreads();
    {
        const int lane = tid & 63;
        float bgq[3][4];
        #pragma unroll
        for (int k = 0; k < 3; ++k)
            #pragma unroll
            for (int i = 0; i < 4; ++i)
                bgq[k][i] = bf2f(bg[k * NC + lane * 4 + i]);
        for (int w = wv; w < NV; w += 4) {
            float4 xq = *(const float4*)&h3s[w * 260 + lane * 4];
            const float cw0 = cs4[w * 4], cw1 = cs4[w * 4 + 1], cw2 = cs4[w * 4 + 2];
            xq.x += cw0 * bgq[0][0] + cw1 * bgq[1][0] + cw2 * bgq[2][0];
            xq.y += cw0 * bgq[0][1] + cw1 * bgq[1][1] + cw2 * bgq[2][1];
            xq.z += cw0 * bgq[0][2] + cw1 * bgq[1][2] + cw2 * bgq[2][2];
            xq.w += cw0 * bgq[0][3] + cw1 * bgq[1][3] + cw2 * bgq[2][3];
            float s = xq.x + xq.y + xq.z + xq.w;
            float q = xq.x * xq.x + xq.y * xq.y + xq.z * xq.z + xq.w * xq.w;
            #pragma unroll
            for (int o = 32; o; o >>= 1) { s += __shfl_xor(s, o); q += __shfl_xor(q, o); }
            float mean = s * (1.f / 256.f);
            float var = fmaxf((q - 256.f * mean * mean) * (1.f / 255.f), 0.f);
            float inv = 1.f / (sqrtf(var) + LN_EPS);
            float o0 = bf2f(g3[lane * 4 + 0]) * (xq.x - mean) * inv + bf2f(b3[lane * 4 + 0]);
            float o1 = bf2f(g3[lane * 4 + 1]) * (xq.y - mean) * inv + bf2f(b3[lane * 4 + 1]);
            float o2 = bf2f(g3[lane * 4 + 2]) * (xq.z - mean) * inv + bf2f(b3[lane * 4 + 2]);
            float o3 = bf2f(g3[lane * 4 + 3]) * (xq.w - mean) * inv + bf2f(b3[lane * 4 + 3]);
            float* op = outp + (((size_t)(b * NT + t)) * NV + w) * NC + lane * 4;
            *(float4*)op = make_float4(o0, o1, o2, o3);
        }
    }
}

extern "C" void kernel_launch(void* const* d_in, const int* in_sizes, int n_in,
                              void* d_out, int out_size, void* d_ws, size_t ws_size,
                              hipStream_t stream)
{
    const size_t NTOK = (size_t)NB * NT * NV;   // 51200
    char* ws = (char*)d_ws;
    int* flag = (int*)ws;
    ush* A2 = (ush*)(ws + 256);                 // [32][96] bf16, 6KB
    float* cs4 = (float*)(ws + 256 + 6144);     // [25][4] f32, 400B
    ush* bufA = (ush*)(ws + 16384);             // [M,768]  78.6MB
    ush* bufB = bufA + NTOK * NKC;              // [M,256]  26.2MB
    ush* conv = bufB + NTOK * NC;

    k_detect<<<1, 256, 0, stream>>>((const uint32*)d_in[0], flag);
    k_convA<<<1, 256, 0, stream>>>(d_in[2], A2, cs4, flag);

    // ---- one-launch conversion table ----
    CvTab tab;
    int nent = 0, blk = 0;
    ush* p = conv;
    const ush* cp[18] = {};
    auto add = [&](int idx, int n, int K, int N, ush*& dst_out) {
        tab.e[nent] = { d_in[idx], p, n, K, N, blk };
        dst_out = p;
        blk += (K == 0) ? (n + 2047) / 2048 : (n + 1023) / 1024;
        p += (size_t)((n + 7) & ~7);
        ++nent;
    };
    ush* d;
    add(0, NB * NT * NV * NCIN, 0, 0, d);  cp[0] = d;
    add(1, NB * NTM * NV * NCM, 0, 0, d);  cp[1] = d;
    add(15, NKC, 0, 0, d);                 cp[15] = d;
    add(7, NC, 0, 0, d);  cp[7] = d;
    add(8, NC, 0, 0, d);  cp[8] = d;
    add(12, NC, 0, 0, d); cp[12] = d;
    add(13, NC, 0, 0, d); cp[13] = d;
    add(16, NC, 0, 0, d); cp[16] = d;
    add(17, NC, 0, 0, d); cp[17] = d;
    ush* w1t;
    add(4, NCIN * NC, NCIN, NC, w1t);      // [256][64] q
    add(5, NCIN * NC, NCIN, NC, d);        // k  (contiguous after q)
    add(6, NCIN * NC, NCIN, NC, d);        // v
    ush* wq2t;
    add(9, NC * NC, NC, NC, wq2t);         // [256][256]
    ush* wkv2t;
    add(10, NCM * NC, NCM, NC, wkv2t);     // [256][256] k
    add(11, NCM * NC, NCM, NC, d);         // v (contiguous)
    ush* wgt;
    add(14, NC * NKC, NC, NKC, wgt);       // [768][256]
    k_convall<<<blk, 256, 0, stream>>>(tab, flag);

    const int M = (int)NTOK;
    // stage 1: qkv1 = x @ [Wq1|Wk1|Wv1]  -> bufA [M,768]
    k_gemm<<<dim3(6, M / 128), 256, 0, stream>>>(cp[0], w1t, bufA, M, NCIN, NKC);
    k_attn_mfma<1><<<dim3(NV, NH / 4, NB), 256, 0, stream>>>(bufA, bufB);
    k_ln<<<M / 4, 256, 0, stream>>>(bufB, cp[7], cp[8]);
    // stage 2: q2 = h1 @ Wq2 (cols 0-255); kv2 = m @ [Wk2|Wv2] (cols 256-767)
    k_gemm<<<dim3(2, M / 128), 256, 0, stream>>>(bufB, wq2t, bufA, M, NC, NKC);
    k_gemm<<<dim3(4, M / 128), 256, 0, stream>>>(cp[1], wkv2t, bufA + 256, M, NCM, NKC);
    k_attn_mfma<0><<<dim3(NV, NH / 4, NB), 256, 0, stream>>>(bufA, bufB);
    k_ln<<<M / 4, 256, 0, stream>>>(bufB, cp[12], cp[13]);
    // stage 3: xw = h2 @ Wg -> bufA [M,768]; then MFMA GCN + LN -> out
    k_gemm<<<dim3(6, M / 128), 256, 0, stream>>>(bufB, wgt, bufA, M, NC, NKC);
    k_gcn_mfma<<<dim3(NT, NB), 256, 0, stream>>>(bufA, A2, cs4, cp[15], cp[16], cp[17],
                                                 (float*)d_out);
}

// Round 14
// 270.086 us; speedup vs baseline: 1.3896x; 1.0001x over previous
//
#include <hip/hip_runtime.h>
#include <hip/hip_bf16.h>

typedef unsigned short ush;
typedef unsigned int uint32;
typedef __attribute__((ext_vector_type(8))) short s8v;   // 8 bf16 (4 VGPRs)
typedef __attribute__((ext_vector_type(4))) float f4v;   // MFMA accumulator

#define NB 16
#define NT 128
#define NTM 128
#define NV 25
#define NCIN 64
#define NCM 256
#define NH 8
#define ND 32
#define NC 256
#define NK 3
#define NKC 768
#define LN_EPS 1e-6f
#define QSCALE 0.17677669529663687f

__device__ __forceinline__ float bf2f(ush u) {
    union { uint32 i; float f; } x; x.i = ((uint32)u) << 16; return x.f;
}
__device__ __forceinline__ ush f2bf(float f) {
    union { float f; uint32 i; } x; x.f = f;
    uint32 r = x.i + 0x7FFFu + ((x.i >> 16) & 1u);
    return (ush)(r >> 16);
}
__device__ __forceinline__ uint32 pack2(float a, float b) {
    return (uint32)f2bf(a) | ((uint32)f2bf(b) << 16);
}

// -------- dtype detector (f32 vs bf16 device buffers) --------
__global__ __launch_bounds__(256) void k_detect(const uint32* __restrict__ xw,
                                               int* __restrict__ flag)
{
    __shared__ int cnt;
    if (threadIdx.x == 0) cnt = 0;
    __syncthreads();
    int c = 0;
    for (int i = 0; i < 4; ++i) {
        uint32 u = xw[threadIdx.x + 256 * i];
        uint32 e = (u >> 7) & 0xFF;
        c += (e >= 100 && e <= 135) ? 1 : 0;
    }
    atomicAdd(&cnt, c);
    __syncthreads();
    if (threadIdx.x == 0) *flag = (cnt > 700) ? 1 : 0;   // 1 = bf16, 0 = f32
}

// A [k][v][w] -> A2 bf16 [32 w][96 kk], kk = k*32+v (pad w>=25, v>=25 with 0)
//             + cs4[w][4]: cs4[w*4+k] = sum_v A[k][v][w]
__global__ __launch_bounds__(256) void k_convA(const void* __restrict__ src,
                                               ush* __restrict__ A2,
                                               float* __restrict__ cs4,
                                               const int* __restrict__ flag)
{
    const bool isbf = (*flag != 0);
    const int tid = threadIdx.x;
    __shared__ float As[1875];
    for (int i = tid; i < 1875; i += 256)
        As[i] = isbf ? bf2f(((const ush*)src)[i]) : ((const float*)src)[i];
    __syncthreads();
    for (int j = tid; j < 32 * 96; j += 256) {
        int w = j / 96, kk = j - w * 96, k = kk >> 5, v = kk & 31;
        float val = (w < NV && v < NV) ? As[k * 625 + v * 25 + w] : 0.f;
        A2[j] = f2bf(val);
    }
    for (int j = tid; j < 100; j += 256) {
        int w = j >> 2, k = j & 3;
        float s = 0.f;
        if (k < 3)
            for (int v = 0; v < NV; ++v) s += As[k * 625 + v * 25 + w];
        cs4[j] = s;
    }
}

// -------- single-launch converter --------
struct CvEnt { const void* src; ush* dst; int n; int K; int N; int blk0; };
struct CvTab { CvEnt e[16]; };

__global__ __launch_bounds__(256) void k_convall(CvTab tab, const int* __restrict__ flag)
{
    const bool isbf = (*flag != 0);
    const int bi = (int)blockIdx.x;
    int ei = 0;
    #pragma unroll
    for (int i = 1; i < 16; ++i) if (bi >= tab.e[i].blk0) ei = i;
    const CvEnt& e = tab.e[ei];
    if (e.K == 0) {
        const int idx = (bi - e.blk0) * 2048 + (int)threadIdx.x * 8;
        if (idx >= e.n) return;
        if (isbf) {
            *(uint4*)&e.dst[idx] = *(const uint4*)((const ush*)e.src + idx);
        } else {
            const float* s = (const float*)e.src + idx;
            uint4 a = *(const uint4*)s;
            uint4 b = *(const uint4*)(s + 4);
            uint4 o;
            o.x = pack2(((float*)&a)[0], ((float*)&a)[1]);
            o.y = pack2(((float*)&a)[2], ((float*)&a)[3]);
            o.z = pack2(((float*)&b)[0], ((float*)&b)[1]);
            o.w = pack2(((float*)&b)[2], ((float*)&b)[3]);
            *(uint4*)&e.dst[idx] = o;
        }
    } else {
        const int s4 = (bi - e.blk0) * 1024 + (int)threadIdx.x * 4;
        if (s4 >= e.n) return;
        const int k = s4 / e.N, n0 = s4 - k * e.N;
        float v0, v1, v2, v3;
        if (isbf) {
            const ush* s = (const ush*)e.src + s4;
            v0 = bf2f(s[0]); v1 = bf2f(s[1]); v2 = bf2f(s[2]); v3 = bf2f(s[3]);
        } else {
            float4 f = *(const float4*)((const float*)e.src + s4);
            v0 = f.x; v1 = f.y; v2 = f.z; v3 = f.w;
        }
        ush* d = e.dst + (size_t)n0 * e.K + k;
        d[0] = f2bf(v0);
        d[e.K] = f2bf(v1);
        d[2 * e.K] = f2bf(v2);
        d[3 * e.K] = f2bf(v3);
    }
}

// -------- MFMA GEMM: C[M, cols n0..] = A[M,K] @ Bt[N,K]^T --------
__global__ __launch_bounds__(256) void k_gemm(
    const ush* __restrict__ A, const ush* __restrict__ Bt, ush* __restrict__ C,
    int M, int K, int ldC)
{
    const int n0 = blockIdx.x * 128, m0 = blockIdx.y * 128;
    const int tid = threadIdx.x, w = tid >> 6, l = tid & 63;
    __shared__ ush As[8192], Bs[8192];
    const char* AsB = (const char*)As;
    const char* BsB = (const char*)Bs;
    const int rl = l >> 3, cc = l & 7;
    f4v acc[4][4] = {};
    const int wm = w >> 1, wn = w & 1;

    for (int kt = 0; kt < K; kt += 64) {
        __syncthreads();
        #pragma unroll
        for (int j = 0; j < 4; ++j) {
            const int r = (w * 4 + j) * 8 + rl;
            const int sc = (cc ^ (r & 7)) * 8;
            const ush* ga = &A[(size_t)(m0 + r) * K + kt + sc];
            const ush* gb = &Bt[(size_t)(n0 + r) * K + kt + sc];
            __builtin_amdgcn_global_load_lds(
                (const __attribute__((address_space(1))) uint32*)ga,
                (__attribute__((address_space(3))) uint32*)&As[(w * 4 + j) * 512], 16, 0, 0);
            __builtin_amdgcn_global_load_lds(
                (const __attribute__((address_space(1))) uint32*)gb,
                (__attribute__((address_space(3))) uint32*)&Bs[(w * 4 + j) * 512], 16, 0, 0);
        }
        __syncthreads();
        #pragma unroll
        for (int ks = 0; ks < 2; ++ks) {
            const int ko = ks * 64 + (l >> 4) * 16;
            s8v a[4], b[4];
            #pragma unroll
            for (int mi = 0; mi < 4; ++mi) {
                const int ra = wm * 64 + mi * 16 + (l & 15);
                a[mi] = *(const s8v*)(AsB + ra * 128 + (ko ^ ((ra & 7) << 4)));
            }
            #pragma unroll
            for (int ni = 0; ni < 4; ++ni) {
                const int rb = wn * 64 + ni * 16 + (l & 15);
                b[ni] = *(const s8v*)(BsB + rb * 128 + (ko ^ ((rb & 7) << 4)));
            }
            #pragma unroll
            for (int mi = 0; mi < 4; ++mi)
                #pragma unroll
                for (int ni = 0; ni < 4; ++ni)
                    acc[mi][ni] = __builtin_amdgcn_mfma_f32_16x16x32_bf16(a[mi], b[ni],
                                                                          acc[mi][ni], 0, 0, 0);
        }
    }
    const int col = n0 + wn * 64 + (l & 15);
    #pragma unroll
    for (int mi = 0; mi < 4; ++mi) {
        const int row_base = m0 + wm * 64 + mi * 16 + (l >> 4) * 4;
        #pragma unroll
        for (int ni = 0; ni < 4; ++ni)
            #pragma unroll
            for (int r = 0; r < 4; ++r)
                C[(size_t)(row_base + r) * ldC + col + ni * 16] = f2bf(acc[mi][ni][r]);
    }
}

// -------- MFMA attention: 8 waves/block = 4 heads x 2 t-halves --------
// Wave (h, th) computes output rows t in [th*64, th*64+64). Head-pair waves
// share one LDS V tile. MASKED: tile-level triangle skip (si <= t16).
template<int MASKED>
__global__ __launch_bounds__(512) void k_attn_mfma(
    const ush* __restrict__ QKV, ush* __restrict__ O)
{
    const int v = blockIdx.x, hq = blockIdx.y, b = blockIdx.z;
    const int tid = threadIdx.x, wv = tid >> 6, l = tid & 63;
    const int hs = wv >> 1, th = wv & 1;
    const int h = hq * 4 + hs;
    const int g = l >> 4, c = l & 15;
    __shared__ ush Vs[4][NT * ND];   // 32 KB: per-head V tile, linear [128][32]
    const size_t tokStride = (size_t)NV * NKC;
    const ush* base = QKV + ((size_t)b * NT * NV + v) * NKC;

    // stage V: each wave stages its t-half's rows (4 x 16-row chunks)
    const int vrow = l >> 2, vch = (l & 3) * 8;
    #pragma unroll
    for (int i = 0; i < 4; ++i) {
        const int row = 16 * (4 * th + i) + vrow;
        s8v rv = *(const s8v*)(base + (size_t)row * tokStride + 512 + h * ND + vch);
        *(s8v*)&Vs[hs][row * ND + vch] = rv;
    }
    // K fragments from global (full s range, duplicated per t-half wave)
    s8v kf[8];
    const int koff = 256 + h * ND + g * 8;
    #pragma unroll
    for (int si = 0; si < 8; ++si)
        kf[si] = *(const s8v*)(base + (size_t)(16 * si + c) * tokStride + koff);
    __syncthreads();
    // V^T fragments from LDS: vf[ks][ni][j] = V[32ks+8g+j][16ni+c]
    s8v vf[4][2];
    #pragma unroll
    for (int ks = 0; ks < 4; ++ks)
        #pragma unroll
        for (int ni = 0; ni < 2; ++ni) {
            s8v tmp;
            #pragma unroll
            for (int j = 0; j < 8; ++j)
                tmp[j] = (short)Vs[hs][(32 * ks + 8 * g + j) * ND + 16 * ni + c];
            vf[ks][ni] = tmp;
        }

    ush* og = O + ((size_t)b * NT * NV + v) * NC + h * ND;
    const int qoff = h * ND + g * 8;
    const int ga = (g & 1) * 2;
    const int l1 = ga * 16 + c, l2 = l1 + 16;
    const bool hisel = (g >> 1) != 0;

    for (int i = 0; i < 4; ++i) {
        const int t16 = 4 * th + i;
        s8v qf = *(const s8v*)(base + (size_t)(16 * t16 + c) * tokStride + qoff);
        f4v st[8];
        #pragma unroll
        for (int si = 0; si < 8; ++si) {
            if (MASKED && si > t16) { st[si] = (f4v){0.f, 0.f, 0.f, 0.f}; continue; }
            st[si] = __builtin_amdgcn_mfma_f32_16x16x32_bf16(kf[si], qf,
                                                             (f4v){0.f, 0.f, 0.f, 0.f}, 0, 0, 0);
        }
        const int t = 16 * t16 + c;
        if (MASKED) {
            #pragma unroll
            for (int si = 0; si < 8; ++si) {
                if (si > t16) continue;
                #pragma unroll
                for (int r = 0; r < 4; ++r)
                    if (16 * si + 4 * g + r > t) st[si][r] = -1e30f;
            }
        }
        float mx = -1e30f;
        #pragma unroll
        for (int si = 0; si < 8; ++si) {
            if (MASKED && si > t16) continue;
            #pragma unroll
            for (int r = 0; r < 4; ++r) mx = fmaxf(mx, st[si][r]);
        }
        mx = fmaxf(mx, __shfl_xor(mx, 16));
        mx = fmaxf(mx, __shfl_xor(mx, 32));
        float sm = 0.f;
        #pragma unroll
        for (int si = 0; si < 8; ++si) {
            if (MASKED && si > t16) continue;
            #pragma unroll
            for (int r = 0; r < 4; ++r) {
                float e = __expf((st[si][r] - mx) * QSCALE);
                st[si][r] = e;
                sm += e;
            }
        }
        sm += __shfl_xor(sm, 16);
        sm += __shfl_xor(sm, 32);
        const float inv = 1.f / sm;
        uint32 u[8][2];
        #pragma unroll
        for (int si = 0; si < 8; ++si) {
            if (MASKED && si > t16) { u[si][0] = 0u; u[si][1] = 0u; continue; }
            float e0 = st[si][0] * inv, e1 = st[si][1] * inv;
            float e2 = st[si][2] * inv, e3 = st[si][3] * inv;
            asm("v_cvt_pk_bf16_f32 %0, %1, %2" : "=v"(u[si][0]) : "v"(e0), "v"(e1));
            asm("v_cvt_pk_bf16_f32 %0, %1, %2" : "=v"(u[si][1]) : "v"(e2), "v"(e3));
        }
        f4v o[2] = {};
        #pragma unroll
        for (int ks = 0; ks < 4; ++ks) {
            if (MASKED && 2 * ks > t16) continue;   // both u-tiles zero
            uint32 w0a = __shfl(u[2 * ks][0], l1),     w0b = __shfl(u[2 * ks][1], l1);
            uint32 w0c = __shfl(u[2 * ks][0], l2),     w0d = __shfl(u[2 * ks][1], l2);
            uint32 w1a = __shfl(u[2 * ks + 1][0], l1), w1b = __shfl(u[2 * ks + 1][1], l1);
            uint32 w1c = __shfl(u[2 * ks + 1][0], l2), w1d = __shfl(u[2 * ks + 1][1], l2);
            union { uint32 w[4]; s8v s; } pa;
            pa.w[0] = hisel ? w1a : w0a;
            pa.w[1] = hisel ? w1b : w0b;
            pa.w[2] = hisel ? w1c : w0c;
            pa.w[3] = hisel ? w1d : w0d;
            o[0] = __builtin_amdgcn_mfma_f32_16x16x32_bf16(pa.s, vf[ks][0], o[0], 0, 0, 0);
            o[1] = __builtin_amdgcn_mfma_f32_16x16x32_bf16(pa.s, vf[ks][1], o[1], 0, 0, 0);
        }
        #pragma unroll
        for (int ni = 0; ni < 2; ++ni)
            #pragma unroll
            for (int r = 0; r < 4; ++r)
                og[(size_t)(16 * t16 + 4 * g + r) * (NV * NC) + 16 * ni + c] = f2bf(o[ni][r]);
    }
}

// ---------------- row LayerNorm (unbiased std), in place, 1 wave = 1 row ----------------
__global__ __launch_bounds__(256) void k_ln(
    ush* __restrict__ buf, const ush* __restrict__ g, const ush* __restrict__ bb)
{
    const int row = blockIdx.x * 4 + (threadIdx.x >> 6);
    const int lane = threadIdx.x & 63;
    ush* p = buf + (size_t)row * NC + lane * 4;
    uint2 u = *(uint2*)p;
    float x0 = bf2f((ush)(u.x & 0xffff)), x1 = bf2f((ush)(u.x >> 16));
    float x2 = bf2f((ush)(u.y & 0xffff)), x3 = bf2f((ush)(u.y >> 16));
    float s = x0 + x1 + x2 + x3;
    float q = x0 * x0 + x1 * x1 + x2 * x2 + x3 * x3;
    #pragma unroll
    for (int o = 32; o; o >>= 1) { s += __shfl_xor(s, o); q += __shfl_xor(q, o); }
    float mean = s * (1.f / 256.f);
    float var = fmaxf((q - 256.f * mean * mean) * (1.f / 255.f), 0.f);
    float inv = 1.f / (sqrtf(var) + LN_EPS);
    float o0 = bf2f(g[lane * 4 + 0]) * (x0 - mean) * inv + bf2f(bb[lane * 4 + 0]);
    float o1 = bf2f(g[lane * 4 + 1]) * (x1 - mean) * inv + bf2f(bb[lane * 4 + 1]);
    float o2 = bf2f(g[lane * 4 + 2]) * (x2 - mean) * inv + bf2f(bb[lane * 4 + 2]);
    float o3 = bf2f(g[lane * 4 + 3]) * (x3 - mean) * inv + bf2f(bb[lane * 4 + 3]);
    uint32 lo = (uint32)f2bf(o0) | ((uint32)f2bf(o1) << 16);
    uint32 hi = (uint32)f2bf(o2) | ((uint32)f2bf(o3) << 16);
    *(uint2*)p = make_uint2(lo, hi);
}

// -------- GCN via MFMA: per (b,t): h3[32 w][256 c] = A2[32][96] @ X[96][256] --------
__global__ __launch_bounds__(256) void k_gcn_mfma(
    const ush* __restrict__ xw, const ush* __restrict__ A2,
    const float* __restrict__ cs4,
    const ush* __restrict__ bg, const ush* __restrict__ g3, const ush* __restrict__ b3,
    float* __restrict__ outp)
{
    const int t = blockIdx.x, b = blockIdx.y;
    const int tid = threadIdx.x;
    __shared__ uint4 Xs4[2400];                 // 38.4KB: X tile, swizzled
    char* Xs = (char*)Xs4;
    float* h3s = (float*)Xs4;                   // [25][260] f32 overlay after barrier
    const int l = tid & 63, wv = tid >> 6, g = l >> 4, c4 = l & 15;

    s8v af[2][3];
    #pragma unroll
    for (int mi = 0; mi < 2; ++mi)
        #pragma unroll
        for (int ks = 0; ks < 3; ++ks)
            af[mi][ks] = *(const s8v*)&A2[(mi * 16 + c4) * 96 + ks * 32 + g * 8];

    const ush* xr = xw + ((size_t)(b * NT + t)) * NV * NKC;
    for (int i = tid; i < 2400; i += 256) {
        int v = i / 96, c8 = i - v * 96;
        uint32 off = (uint32)(v * 1536 + c8 * 16) ^ (((v >> 3) & 3) << 4);
        *(uint4*)(Xs + off) = *(const uint4*)&xr[(size_t)v * NKC + c8 * 8];
    }
    __syncthreads();

    f4v acc[2][4] = {};
    const int c0 = wv * 64;
    #pragma unroll
    for (int ks = 0; ks < 3; ++ks) {
        #pragma unroll
        for (int ni = 0; ni < 4; ++ni) {
            const int c = c0 + ni * 16 + c4;
            s8v bfr;
            #pragma unroll
            for (int j = 0; j < 8; ++j) {
                int v = g * 8 + j; if (v > 24) v = 24;
                uint32 off = (uint32)(v * 1536 + ks * 512 + c * 2) ^ (((v >> 3) & 3) << 4);
                bfr[j] = *(const short*)(Xs + off);
            }
            acc[0][ni] = __builtin_amdgcn_mfma_f32_16x16x32_bf16(af[0][ks], bfr, acc[0][ni], 0, 0, 0);
            acc[1][ni] = __builtin_amdgcn_mfma_f32_16x16x32_bf16(af[1][ks], bfr, acc[1][ni], 0, 0, 0);
        }
    }
    __syncthreads();
    #pragma unroll
    for (int mi = 0; mi < 2; ++mi)
        #pragma unroll
        for (int r = 0; r < 4; ++r) {
            const int w = mi * 16 + g * 4 + r;
            if (w < NV) {
                #pragma unroll
                for (int ni = 0; ni < 4; ++ni)
                    h3s[w * 260 + c0 + ni * 16 + c4] = acc[mi][ni][r];
            }
        }
    __syncthreads();
    {
        const int lane = tid & 63;
        float bgq[3][4];
        #pragma unroll
        for (int k = 0; k < 3; ++k)
            #pragma unroll
            for (int i = 0; i < 4; ++i)
                bgq[k][i] = bf2f(bg[k * NC + lane * 4 + i]);
        for (int w = wv; w < NV; w += 4) {
            float4 xq = *(const float4*)&h3s[w * 260 + lane * 4];
            const float cw0 = cs4[w * 4], cw1 = cs4[w * 4 + 1], cw2 = cs4[w * 4 + 2];
            xq.x += cw0 * bgq[0][0] + cw1 * bgq[1][0] + cw2 * bgq[2][0];
            xq.y += cw0 * bgq[0][1] + cw1 * bgq[1][1] + cw2 * bgq[2][1];
            xq.z += cw0 * bgq[0][2] + cw1 * bgq[1][2] + cw2 * bgq[2][2];
            xq.w += cw0 * bgq[0][3] + cw1 * bgq[1][3] + cw2 * bgq[2][3];
            float s = xq.x + xq.y + xq.z + xq.w;
            float q = xq.x * xq.x + xq.y * xq.y + xq.z * xq.z + xq.w * xq.w;
            #pragma unroll
            for (int o = 32; o; o >>= 1) { s += __shfl_xor(s, o); q += __shfl_xor(q, o); }
            float mean = s * (1.f / 256.f);
            float var = fmaxf((q - 256.f * mean * mean) * (1.f / 255.f), 0.f);
            float inv = 1.f / (sqrtf(var) + LN_EPS);
            float o0 = bf2f(g3[lane * 4 + 0]) * (xq.x - mean) * inv + bf2f(b3[lane * 4 + 0]);
            float o1 = bf2f(g3[lane * 4 + 1]) * (xq.y - mean) * inv + bf2f(b3[lane * 4 + 1]);
            float o2 = bf2f(g3[lane * 4 + 2]) * (xq.z - mean) * inv + bf2f(b3[lane * 4 + 2]);
            float o3 = bf2f(g3[lane * 4 + 3]) * (xq.w - mean) * inv + bf2f(b3[lane * 4 + 3]);
            float* op = outp + (((size_t)(b * NT + t)) * NV + w) * NC + lane * 4;
            *(float4*)op = make_float4(o0, o1, o2, o3);
        }
    }
}

extern "C" void kernel_launch(void* const* d_in, const int* in_sizes, int n_in,
                              void* d_out, int out_size, void* d_ws, size_t ws_size,
                              hipStream_t stream)
{
    const size_t NTOK = (size_t)NB * NT * NV;   // 51200
    char* ws = (char*)d_ws;
    int* flag = (int*)ws;
    ush* A2 = (ush*)(ws + 256);                 // [32][96] bf16, 6KB
    float* cs4 = (float*)(ws + 256 + 6144);     // [25][4] f32, 400B
    ush* bufA = (ush*)(ws + 16384);             // [M,768]  78.6MB
    ush* bufB = bufA + NTOK * NKC;              // [M,256]  26.2MB
    ush* conv = bufB + NTOK * NC;

    k_detect<<<1, 256, 0, stream>>>((const uint32*)d_in[0], flag);
    k_convA<<<1, 256, 0, stream>>>(d_in[2], A2, cs4, flag);

    // ---- one-launch conversion table ----
    CvTab tab;
    int nent = 0, blk = 0;
    ush* p = conv;
    const ush* cp[18] = {};
    auto add = [&](int idx, int n, int K, int N, ush*& dst_out) {
        tab.e[nent] = { d_in[idx], p, n, K, N, blk };
        dst_out = p;
        blk += (K == 0) ? (n + 2047) / 2048 : (n + 1023) / 1024;
        p += (size_t)((n + 7) & ~7);
        ++nent;
    };
    ush* d;
    add(0, NB * NT * NV * NCIN, 0, 0, d);  cp[0] = d;
    add(1, NB * NTM * NV * NCM, 0, 0, d);  cp[1] = d;
    add(15, NKC, 0, 0, d);                 cp[15] = d;
    add(7, NC, 0, 0, d);  cp[7] = d;
    add(8, NC, 0, 0, d);  cp[8] = d;
    add(12, NC, 0, 0, d); cp[12] = d;
    add(13, NC, 0, 0, d); cp[13] = d;
    add(16, NC, 0, 0, d); cp[16] = d;
    add(17, NC, 0, 0, d); cp[17] = d;
    ush* w1t;
    add(4, NCIN * NC, NCIN, NC, w1t);      // [256][64] q
    add(5, NCIN * NC, NCIN, NC, d);        // k  (contiguous after q)
    add(6, NCIN * NC, NCIN, NC, d);        // v
    ush* wq2t;
    add(9, NC * NC, NC, NC, wq2t);         // [256][256]
    ush* wkv2t;
    add(10, NCM * NC, NCM, NC, wkv2t);     // [256][256] k
    add(11, NCM * NC, NCM, NC, d);         // v (contiguous)
    ush* wgt;
    add(14, NC * NKC, NC, NKC, wgt);       // [768][256]
    k_convall<<<blk, 256, 0, stream>>>(tab, flag);

    const int M = (int)NTOK;
    // stage 1: qkv1 = x @ [Wq1|Wk1|Wv1]  -> bufA [M,768]
    k_gemm<<<dim3(6, M / 128), 256, 0, stream>>>(cp[0], w1t, bufA, M, NCIN, NKC);
    k_attn_mfma<1><<<dim3(NV, NH / 4, NB), 512, 0, stream>>>(bufA, bufB);
    k_ln<<<M / 4, 256, 0, stream>>>(bufB, cp[7], cp[8]);
    // stage 2: q2 = h1 @ Wq2 (cols 0-255); kv2 = m @ [Wk2|Wv2] (cols 256-767)
    k_gemm<<<dim3(2, M / 128), 256, 0, stream>>>(bufB, wq2t, bufA, M, NC, NKC);
    k_gemm<<<dim3(4, M / 128), 256, 0, stream>>>(cp[1], wkv2t, bufA + 256, M, NCM, NKC);
    k_attn_mfma<0><<<dim3(NV, NH / 4, NB), 512, 0, stream>>>(bufA, bufB);
    k_ln<<<M / 4, 256, 0, stream>>>(bufB, cp[12], cp[13]);
    // stage 3: xw = h2 @ Wg -> bufA [M,768]; then MFMA GCN + LN -> out
    k_gemm<<<dim3(6, M / 128), 256, 0, stream>>>(bufB, wgt, bufA, M, NC, NKC);
    k_gcn_mfma<<<dim3(NT, NB), 256, 0, stream>>>(bufA, A2, cs4, cp[15], cp[16], cp[17],
                                                 (float*)d_out);
}